// Round 3
// baseline (1063.840 us; speedup 1.0000x reference)
//
#include <hip/hip_runtime.h>

// ---------- types ----------
typedef short short8 __attribute__((ext_vector_type(8)));
typedef float f32x4 __attribute__((ext_vector_type(4)));
typedef unsigned int u32x4 __attribute__((ext_vector_type(4)));
typedef unsigned short u16x4 __attribute__((ext_vector_type(4)));
typedef unsigned short u16x8 __attribute__((ext_vector_type(8)));

// ---------- bf16 helpers ----------
__device__ __forceinline__ unsigned short f2bf(float f) {
  unsigned int u = __builtin_bit_cast(unsigned int, f);
  u += 0x7fffu + ((u >> 16) & 1u);
  return (unsigned short)(u >> 16);
}
__device__ __forceinline__ float bf2f(unsigned short h) {
  unsigned int u = ((unsigned int)h) << 16;
  return __builtin_bit_cast(float, u);
}

// ---------- async global->LDS (16B per lane; LDS dst = wave base + lane*16) ----------
__device__ __forceinline__ void gl16(const unsigned short* g, unsigned short* l) {
  __builtin_amdgcn_global_load_lds((const __attribute__((address_space(1))) unsigned int*)g,
                                   (__attribute__((address_space(3))) unsigned int*)l, 16, 0, 0);
}

// ---------- problem constants ----------
#define BB 4
#define SS 2048
#define DD 2048
#define HH 16
#define HD 128
#define MM (BB * SS)  // 8192

// ---------- merged cast fp32 -> bf16 (x + 4 weights) ----------
__global__ void cast_all(const float* __restrict__ x, const float* __restrict__ wq,
                         const float* __restrict__ wk, const float* __restrict__ wv,
                         const float* __restrict__ wo, unsigned short* __restrict__ xb,
                         unsigned short* __restrict__ wqb, unsigned short* __restrict__ wkb,
                         unsigned short* __restrict__ wvb, unsigned short* __restrict__ wob) {
  int i = blockIdx.x * blockDim.x + threadIdx.x;
  const int X4 = (MM * DD) / 4;  // 4194304
  const int W4 = (DD * DD) / 4;  // 1048576
  const float* src;
  unsigned short* dst;
  int off;
  if (i < X4) {
    src = x; dst = xb; off = i;
  } else {
    int t = i - X4;
    int w = t >> 20;
    off = t & (W4 - 1);
    src = (w == 0) ? wq : (w == 1) ? wk : (w == 2) ? wv : wo;
    dst = (w == 0) ? wqb : (w == 1) ? wkb : (w == 2) ? wvb : wob;
  }
  f32x4 v = ((const f32x4*)src)[off];
  u16x4 o;
  o[0] = f2bf(v[0]); o[1] = f2bf(v[1]); o[2] = f2bf(v[2]); o[3] = f2bf(v[3]);
  ((u16x4*)dst)[off] = o;
}

// =====================================================================================
// 256x256 8-phase GEMM core (T2 swizzle + T3/T4 counted vmcnt + T5 setprio).
// (unchanged — verified)
// =====================================================================================
#define STGH(P, R0, t, h, moff)                                                     \
  do {                                                                              \
    const unsigned short* _s =                                                      \
        (P) + (size_t)((R0) + (h) * 128 + srow) * DD + (size_t)((t) * 64 + scol);   \
    gl16(_s, lds + (moff) + (h) * 8192 + wvi * 512);                                \
    gl16(_s + (size_t)64 * DD, lds + (moff) + (h) * 8192 + 4096 + wvi * 512);       \
  } while (0)

#define BARRIER asm volatile("s_barrier" ::: "memory")

__device__ __forceinline__ void gemm_core(const unsigned short* __restrict__ Ap,
                                          const unsigned short* __restrict__ Bp,
                                          unsigned short* lds, int rt, int ct,
                                          f32x4 (&acc)[8][4]) {
  const int tid = threadIdx.x;
  const int lane = tid & 63, wvi = tid >> 6;
  const int wm = wvi >> 2, wn = wvi & 3;
  const int quad = lane >> 4, l16 = lane & 15;
  const int srow = wvi * 8 + (lane >> 3);
  const int scol = ((lane & 7) ^ (lane >> 3)) << 3;
  const int ck0 = (quad ^ (l16 & 7)) << 3;
  const int ck1 = ((4 + quad) ^ (l16 & 7)) << 3;
  const int aro = (wm * 128 + l16) << 6;
  const int bro = (wn * 64 + l16) << 6;
  const int rb = rt * 256, cb = ct * 256;

#pragma unroll
  for (int i = 0; i < 8; ++i)
#pragma unroll
    for (int j = 0; j < 4; ++j) acc[i][j] = f32x4{0.f, 0.f, 0.f, 0.f};

  STGH(Bp, cb, 0, 0, 16384);
  STGH(Bp, cb, 0, 1, 16384);
  STGH(Ap, rb, 0, 0, 0);
  STGH(Ap, rb, 0, 1, 0);
  STGH(Bp, cb, 1, 0, 49152);
  STGH(Bp, cb, 1, 1, 49152);
  asm volatile("s_waitcnt vmcnt(4)" ::: "memory");
  BARRIER;

#pragma unroll 2
  for (int t = 0; t < 32; ++t) {
    const unsigned short* ab = lds + ((t & 1) << 15);
    const unsigned short* bb = ab + 16384;
    const int pn = ((t + 1) & 1) << 15;
    const int pc = ((t & 1) << 15) + 16384;
    short8 aq[4][2], b0f[2][2], b1f[2][2];

    // ---------- phase 0: quadrant (qm0,qn0) ----------
#pragma unroll
    for (int mi = 0; mi < 4; ++mi) {
      aq[mi][0] = __builtin_bit_cast(short8, *(const u32x4*)(ab + aro + mi * 1024 + ck0));
      aq[mi][1] = __builtin_bit_cast(short8, *(const u32x4*)(ab + aro + mi * 1024 + ck1));
    }
#pragma unroll
    for (int ni = 0; ni < 2; ++ni) {
      b0f[ni][0] = __builtin_bit_cast(short8, *(const u32x4*)(bb + bro + ni * 1024 + ck0));
      b0f[ni][1] = __builtin_bit_cast(short8, *(const u32x4*)(bb + bro + ni * 1024 + ck1));
    }
    if (t < 31) STGH(Ap, rb, t + 1, 0, pn);
    BARRIER;
    __builtin_amdgcn_s_setprio(1);
#pragma unroll
    for (int k = 0; k < 2; ++k)
#pragma unroll
      for (int mi = 0; mi < 4; ++mi)
#pragma unroll
        for (int ni = 0; ni < 2; ++ni)
          acc[mi][ni] =
              __builtin_amdgcn_mfma_f32_16x16x32_bf16(aq[mi][k], b0f[ni][k], acc[mi][ni], 0, 0, 0);
    __builtin_amdgcn_s_setprio(0);
    BARRIER;

    // ---------- phase 1: quadrant (qm0,qn1) ----------
#pragma unroll
    for (int ni = 0; ni < 2; ++ni) {
      b1f[ni][0] = __builtin_bit_cast(short8, *(const u32x4*)(bb + bro + 2048 + ni * 1024 + ck0));
      b1f[ni][1] = __builtin_bit_cast(short8, *(const u32x4*)(bb + bro + 2048 + ni * 1024 + ck1));
    }
    if (t < 31) STGH(Ap, rb, t + 1, 1, pn);
    BARRIER;
    __builtin_amdgcn_s_setprio(1);
#pragma unroll
    for (int k = 0; k < 2; ++k)
#pragma unroll
      for (int mi = 0; mi < 4; ++mi)
#pragma unroll
        for (int ni = 0; ni < 2; ++ni)
          acc[mi][2 + ni] = __builtin_amdgcn_mfma_f32_16x16x32_bf16(aq[mi][k], b1f[ni][k],
                                                                    acc[mi][2 + ni], 0, 0, 0);
    __builtin_amdgcn_s_setprio(0);
    BARRIER;

    // ---------- phase 2: quadrant (qm1,qn1) ----------
#pragma unroll
    for (int mi = 0; mi < 4; ++mi) {
      aq[mi][0] = __builtin_bit_cast(short8, *(const u32x4*)(ab + aro + 4096 + mi * 1024 + ck0));
      aq[mi][1] = __builtin_bit_cast(short8, *(const u32x4*)(ab + aro + 4096 + mi * 1024 + ck1));
    }
    if (t < 30) STGH(Bp, cb, t + 2, 0, pc);
    BARRIER;
    __builtin_amdgcn_s_setprio(1);
#pragma unroll
    for (int k = 0; k < 2; ++k)
#pragma unroll
      for (int mi = 0; mi < 4; ++mi)
#pragma unroll
        for (int ni = 0; ni < 2; ++ni)
          acc[4 + mi][2 + ni] = __builtin_amdgcn_mfma_f32_16x16x32_bf16(
              aq[mi][k], b1f[ni][k], acc[4 + mi][2 + ni], 0, 0, 0);
    __builtin_amdgcn_s_setprio(0);
    BARRIER;

    // ---------- phase 3: quadrant (qm1,qn0); boundary wait ----------
    if (t < 30) STGH(Bp, cb, t + 2, 1, pc);
    BARRIER;
    __builtin_amdgcn_s_setprio(1);
#pragma unroll
    for (int k = 0; k < 2; ++k)
#pragma unroll
      for (int mi = 0; mi < 4; ++mi)
#pragma unroll
        for (int ni = 0; ni < 2; ++ni)
          acc[4 + mi][ni] = __builtin_amdgcn_mfma_f32_16x16x32_bf16(aq[mi][k], b0f[ni][k],
                                                                    acc[4 + mi][ni], 0, 0, 0);
    __builtin_amdgcn_s_setprio(0);
    if (t < 30) {
      asm volatile("s_waitcnt vmcnt(4)" ::: "memory");
      BARRIER;
    } else if (t == 30) {
      asm volatile("s_waitcnt vmcnt(0)" ::: "memory");
      BARRIER;
    }
  }
}

// ---------- QKV GEMM (merged): z=0 Q, z=1 K (standard), z=2 V -> writes V^T [b][h][d][s] ----------
__global__ __launch_bounds__(512, 2) void gemm_qkv(const unsigned short* __restrict__ A,
                                                   const unsigned short* __restrict__ W0,
                                                   const unsigned short* __restrict__ W1,
                                                   const unsigned short* __restrict__ W2,
                                                   unsigned short* __restrict__ q_out,
                                                   unsigned short* __restrict__ k_out,
                                                   unsigned short* __restrict__ v_out) {
  __shared__ unsigned short lds[65536];
  const int ct = blockIdx.x, rt = blockIdx.y, z = blockIdx.z;
  const unsigned short* W = (z == 0) ? W0 : (z == 1) ? W1 : W2;
  unsigned short* outb = (z == 0) ? q_out : (z == 1) ? k_out : v_out;
  f32x4 acc[8][4];
  gemm_core(A, W, lds, rt, ct, acc);

  const int tid = threadIdx.x;
  const int lane = tid & 63, wvi = tid >> 6;
  const int wm = wvi >> 2, wn = wvi & 3;
  const int quad = lane >> 4, l16 = lane & 15;

  if (z != 2) {
    // Q, K: standard (B,H,S,hd) scatter writes
#pragma unroll
    for (int mi = 0; mi < 8; ++mi)
#pragma unroll
      for (int ni = 0; ni < 4; ++ni)
#pragma unroll
        for (int r = 0; r < 4; ++r) {
          int row_g = rt * 256 + wm * 128 + mi * 16 + quad * 4 + r;
          int col_g = ct * 256 + wn * 64 + ni * 16 + l16;
          int b = row_g >> 11, s = row_g & (SS - 1);
          int h = col_g >> 7, d = col_g & (HD - 1);
          outb[(((size_t)(b * HH + h)) * SS + (size_t)s) * HD + (size_t)d] = f2bf(acc[mi][ni][r]);
        }
  } else {
    // V: transpose via LDS, write V^T layout [b][h][d][s] with coalesced 16B stores.
    const int b = rt >> 3;
    const int s_base = (rt & 7) * 256;
    const int hbase = ct * 2;
#pragma unroll
    for (int nh = 0; nh < 2; ++nh) {
      __syncthreads();  // LDS free (gemm staging done / previous half consumed)
      if (((wvi >> 1) & 1) == nh) {  // waves whose cols fall in this 128-col half
        const int halfc = (wvi & 1) * 64;
#pragma unroll
        for (int mi = 0; mi < 8; ++mi)
#pragma unroll
          for (int ni = 0; ni < 4; ++ni)
#pragma unroll
            for (int r = 0; r < 4; ++r) {
              int row_l = wm * 128 + mi * 16 + quad * 4 + r;
              int cl = halfc + ni * 16 + l16;
              lds[row_l * 128 + ((((cl >> 3) ^ (row_l & 15)) << 3) | (cl & 7))] =
                  f2bf(acc[mi][ni][r]);
            }
      }
      __syncthreads();
      const int d_l = tid >> 2;
      const int sb = tid & 3;
      unsigned short* vt =
          v_out + ((size_t)(b * HH + hbase + nh) * HD + (size_t)d_l) * SS + s_base + sb * 64;
#pragma unroll
      for (int j = 0; j < 8; ++j) {
        u16x8 o8;
#pragma unroll
        for (int e = 0; e < 8; ++e) {
          int row_l = sb * 64 + j * 8 + e;
          o8[e] = lds[row_l * 128 + ((((d_l >> 3) ^ (row_l & 15)) << 3) | (d_l & 7))];
        }
        *(u32x4*)(vt + j * 8) = __builtin_bit_cast(u32x4, o8);
      }
    }
  }
}

// ---------- output GEMM: fp32 + bias ----------
__global__ __launch_bounds__(512, 2) void gemm_out(const unsigned short* __restrict__ A,
                                                   const unsigned short* __restrict__ W,
                                                   float* __restrict__ outf,
                                                   const float* __restrict__ bias) {
  __shared__ unsigned short lds[65536];
  const int ct = blockIdx.x, rt = blockIdx.y;
  f32x4 acc[8][4];
  gemm_core(A, W, lds, rt, ct, acc);

  const int tid = threadIdx.x;
  const int lane = tid & 63, wvi = tid >> 6;
  const int wm = wvi >> 2, wn = wvi & 3;
  const int quad = lane >> 4, l16 = lane & 15;
#pragma unroll
  for (int mi = 0; mi < 8; ++mi)
#pragma unroll
    for (int ni = 0; ni < 4; ++ni)
#pragma unroll
      for (int r = 0; r < 4; ++r) {
        int row_g = rt * 256 + wm * 128 + mi * 16 + quad * 4 + r;
        int col_g = ct * 256 + wn * 64 + ni * 16 + l16;
        outf[(size_t)row_g * DD + col_g] = acc[mi][ni][r] + bias[col_g];
      }
}

// ---------- RoPE: 4 pairs (16B) per thread; q pre-scaled by 1/sqrt(hd) ----------
__global__ void rope_kernel(unsigned short* __restrict__ qb, unsigned short* __restrict__ kb) {
  int id = blockIdx.x * blockDim.x + threadIdx.x;
  int c = id & 15;                 // chunk of 8 d-values
  int s = (id >> 4) & (SS - 1);
  int bhb = id >> 15;              // 0..127
  unsigned short* base = (bhb < 64) ? qb : kb;
  float psc = (bhb < 64) ? 0.08838834764831845f : 1.0f;  // fold softmax scale into q
  unsigned short* p = base + ((size_t)(bhb & 63) * SS + s) * HD + c * 8;
  u32x4 w = *(u32x4*)p;
  const float nl = -9.210340371976184f / 64.0f;  // -ln(10000)/64
  u32x4 o;
#pragma unroll
  for (int j = 0; j < 4; ++j) {
    int pi = c * 4 + j;
    float inv = __expf((float)pi * nl);
    float ang = (float)s * inv;
    float cs = __cosf(ang), sn = __sinf(ang);
    float e = bf2f((unsigned short)(w[j] & 0xffffu));
    float od = bf2f((unsigned short)(w[j] >> 16));
    float r1 = (e * cs - od * sn) * psc;
    float r2 = (e * sn + od * cs) * psc;
    o[j] = (unsigned int)f2bf(r1) | ((unsigned int)f2bf(r2) << 16);
  }
  *(u32x4*)p = o;
}

// ---------- Flash attention v6: zero-barrier, direct-from-L2 K/V fragments ----------
// 4 waves x 16 q-rows = 64 q-rows/block; kv-tile 64. Grid 2048, XCD-clustered so each
// XCD's L2 owns 8 bh's worth of K/V (~1MB each). kf = 16B contiguous row-major K;
// vf = 16B contiguous row of V^T [b][h][d][s] (produced by gemm_qkv). Only LDS: per-wave
// private P (2KB, within-wave ordering only) -> NO __syncthreads anywhere. 16KB LDS,
// VGPR<=128 -> up to 16 waves/CU of independent TLP.
__global__ __launch_bounds__(256, 4) void attn_kernel(const unsigned short* __restrict__ qb,
                                                      const unsigned short* __restrict__ kb,
                                                      const unsigned short* __restrict__ vb,
                                                      unsigned short* __restrict__ ctxb) {
  __shared__ unsigned short Pl[4 * 1024];  // per-wave 16x64 P
  const int tid = threadIdx.x;
  const int g0 = blockIdx.x;
  const int g = (g0 & 7) * 256 + (g0 >> 3);  // XCD-cluster: XCD x -> bh in [x*8, x*8+8)
  const int bh = g >> 5;             // 0..63
  const int qa = 31 - (g & 31);      // longest-first within bh
  const int lane = tid & 63, wvi = tid >> 6;
  const int quad = lane >> 4, l16 = lane & 15;
  const size_t bhq = (size_t)bh * SS * HD;  // K (and Q) base; V^T same extent
  const int qrow = qa * 64 + wvi * 16;
  const int b = bh >> 4, h = bh & (HH - 1);
  unsigned short* Pw = Pl + wvi * 1024;
  f32x4 zero = {0.f, 0.f, 0.f, 0.f};

  short8 qf[4];
#pragma unroll
  for (int ks = 0; ks < 4; ++ks)
    qf[ks] = __builtin_bit_cast(
        short8, *(const u32x4*)(qb + bhq + (size_t)(qrow + l16) * HD + ks * 32 + quad * 8));

  f32x4 acc[8];
#pragma unroll
  for (int dt = 0; dt < 8; ++dt) acc[dt] = zero;
  float lpart[4] = {0.f, 0.f, 0.f, 0.f};

  const int ntile = qa + 1;
  for (int kt = 0; kt < ntile; ++kt) {
    const int kv0 = kt * 64;
    const bool dm = (kt == ntile - 1);

    // QK^T: kf fragments straight from global (16 rows x 64B, perfectly coalesced)
    f32x4 sc[4];
#pragma unroll
    for (int nt = 0; nt < 4; ++nt) {
      sc[nt] = zero;
#pragma unroll
      for (int ks = 0; ks < 4; ++ks) {
        short8 kf = __builtin_bit_cast(
            short8, *(const u32x4*)(kb + bhq + (size_t)(kv0 + nt * 16 + l16) * HD + ks * 32 +
                                    quad * 8));
        sc[nt] = __builtin_amdgcn_mfma_f32_16x16x32_bf16(qf[ks], kf, sc[nt], 0, 0, 0);
      }
    }

    // softmax (fixed max), P -> per-wave LDS (XOR swizzle, verified formulas)
    if (dm) {
#pragma unroll
      for (int r = 0; r < 4; ++r) {
        int row = qrow + quad * 4 + r;
        int prow = quad * 4 + r;
#pragma unroll
        for (int nt = 0; nt < 4; ++nt) {
          int col = nt * 16 + l16;
          float pv = (kv0 + col > row) ? 0.f : __expf(sc[nt][r]);
          lpart[r] += pv;
          int el = prow * 64 +
                   ((((nt * 2 + (l16 >> 3)) + prow + 4 * (prow >> 3)) & 7) << 3) + (l16 & 7);
          Pw[el] = f2bf(pv);
        }
      }
    } else {
#pragma unroll
      for (int r = 0; r < 4; ++r) {
        int prow = quad * 4 + r;
#pragma unroll
        for (int nt = 0; nt < 4; ++nt) {
          float pv = __expf(sc[nt][r]);
          lpart[r] += pv;
          int el = prow * 64 +
                   ((((nt * 2 + (l16 >> 3)) + prow + 4 * (prow >> 3)) & 7) << 3) + (l16 & 7);
          Pw[el] = f2bf(pv);
        }
      }
    }

    // PV: pf from private LDS; vf fragments straight from global V^T
#pragma unroll
    for (int ks2 = 0; ks2 < 2; ++ks2) {
      short8 pf = __builtin_bit_cast(
          short8, *(const u32x4*)(Pw + l16 * 64 +
                                  ((((ks2 * 4 + quad) + l16 + 4 * (l16 >> 3)) & 7) << 3)));
#pragma unroll
      for (int dt = 0; dt < 8; ++dt) {
        short8 vf = __builtin_bit_cast(
            short8, *(const u32x4*)(vb + bhq + (size_t)(dt * 16 + l16) * SS + kv0 + ks2 * 32 +
                                    quad * 8));
        acc[dt] = __builtin_amdgcn_mfma_f32_16x16x32_bf16(pf, vf, acc[dt], 0, 0, 0);
      }
    }
  }

  // epilogue: one 16-lane reduction per row, ctx (B,S,D) bf16
  float rl[4];
#pragma unroll
  for (int r = 0; r < 4; ++r) {
    float rs = lpart[r];
#pragma unroll
    for (int off = 1; off < 16; off <<= 1) rs += __shfl_xor(rs, off, 64);
    rl[r] = 1.0f / rs;
  }
#pragma unroll
  for (int dt = 0; dt < 8; ++dt)
#pragma unroll
    for (int r = 0; r < 4; ++r) {
      int row = qrow + quad * 4 + r;
      ctxb[((size_t)(b * SS + row)) * DD + h * HD + dt * 16 + l16] = f2bf(acc[dt][r] * rl[r]);
    }
}

// ---------- launch ----------
extern "C" void kernel_launch(void* const* d_in, const int* in_sizes, int n_in,
                              void* d_out, int out_size, void* d_ws, size_t ws_size,
                              hipStream_t stream) {
  const float* x = (const float*)d_in[0];
  const float* wq = (const float*)d_in[1];
  const float* wk = (const float*)d_in[2];
  const float* wv = (const float*)d_in[3];
  const float* wo = (const float*)d_in[4];
  const float* bo = (const float*)d_in[5];
  float* out = (float*)d_out;

  unsigned short* xb = (unsigned short*)d_ws;
  unsigned short* wqb = xb + (size_t)MM * DD;
  unsigned short* wkb = wqb + (size_t)DD * DD;
  unsigned short* wvb = wkb + (size_t)DD * DD;
  unsigned short* wob = wvb + (size_t)DD * DD;
  unsigned short* qb = wob + (size_t)DD * DD;
  unsigned short* kb = qb + (size_t)MM * DD;
  unsigned short* vb = kb + (size_t)MM * DD;  // holds V^T [b][h][d][s]
  unsigned short* ctxb = vb + (size_t)MM * DD;

  cast_all<<<(2 * MM * DD / 4) / 256, 256, 0, stream>>>(x, wq, wk, wv, wo, xb, wqb, wkb, wvb, wob);

  dim3 gg(DD / 256, MM / 256, 3);
  gemm_qkv<<<gg, 512, 0, stream>>>(xb, wqb, wkb, wvb, qb, kb, vb);

  rope_kernel<<<(128 * 2048 * 16) / 256, 256, 0, stream>>>(qb, kb);

  attn_kernel<<<2048, 256, 0, stream>>>(qb, kb, vb, ctxb);

  dim3 go(DD / 256, MM / 256);
  gemm_out<<<go, 512, 0, stream>>>(ctxb, wob, out, bo);
}

// Round 4
// 572.582 us; speedup vs baseline: 1.8580x; 1.8580x over previous
//
#include <hip/hip_runtime.h>

// ---------- types ----------
typedef short short8 __attribute__((ext_vector_type(8)));
typedef float f32x4 __attribute__((ext_vector_type(4)));
typedef unsigned int u32x4 __attribute__((ext_vector_type(4)));
typedef unsigned short u16x4 __attribute__((ext_vector_type(4)));
typedef unsigned short u16x8 __attribute__((ext_vector_type(8)));

// ---------- bf16 helpers ----------
__device__ __forceinline__ unsigned short f2bf(float f) {
  unsigned int u = __builtin_bit_cast(unsigned int, f);
  u += 0x7fffu + ((u >> 16) & 1u);
  return (unsigned short)(u >> 16);
}
__device__ __forceinline__ float bf2f(unsigned short h) {
  unsigned int u = ((unsigned int)h) << 16;
  return __builtin_bit_cast(float, u);
}

// ---------- async global->LDS (16B per lane; LDS dst = wave base + lane*16) ----------
__device__ __forceinline__ void gl16(const unsigned short* g, unsigned short* l) {
  __builtin_amdgcn_global_load_lds((const __attribute__((address_space(1))) unsigned int*)g,
                                   (__attribute__((address_space(3))) unsigned int*)l, 16, 0, 0);
}

// ---------- problem constants ----------
#define BB 4
#define SS 2048
#define DD 2048
#define HH 16
#define HD 128
#define MM (BB * SS)  // 8192

// ---------- merged cast fp32 -> bf16 (x + 4 weights) ----------
__global__ void cast_all(const float* __restrict__ x, const float* __restrict__ wq,
                         const float* __restrict__ wk, const float* __restrict__ wv,
                         const float* __restrict__ wo, unsigned short* __restrict__ xb,
                         unsigned short* __restrict__ wqb, unsigned short* __restrict__ wkb,
                         unsigned short* __restrict__ wvb, unsigned short* __restrict__ wob) {
  int i = blockIdx.x * blockDim.x + threadIdx.x;
  const int X4 = (MM * DD) / 4;  // 4194304
  const int W4 = (DD * DD) / 4;  // 1048576
  const float* src;
  unsigned short* dst;
  int off;
  if (i < X4) {
    src = x; dst = xb; off = i;
  } else {
    int t = i - X4;
    int w = t >> 20;
    off = t & (W4 - 1);
    src = (w == 0) ? wq : (w == 1) ? wk : (w == 2) ? wv : wo;
    dst = (w == 0) ? wqb : (w == 1) ? wkb : (w == 2) ? wvb : wob;
  }
  f32x4 v = ((const f32x4*)src)[off];
  u16x4 o;
  o[0] = f2bf(v[0]); o[1] = f2bf(v[1]); o[2] = f2bf(v[2]); o[3] = f2bf(v[3]);
  ((u16x4*)dst)[off] = o;
}

// =====================================================================================
// 256x256 8-phase GEMM core (T2 swizzle + T3/T4 counted vmcnt + T5 setprio).
// (unchanged — verified)
// =====================================================================================
#define STGH(P, R0, t, h, moff)                                                     \
  do {                                                                              \
    const unsigned short* _s =                                                      \
        (P) + (size_t)((R0) + (h) * 128 + srow) * DD + (size_t)((t) * 64 + scol);   \
    gl16(_s, lds + (moff) + (h) * 8192 + wvi * 512);                                \
    gl16(_s + (size_t)64 * DD, lds + (moff) + (h) * 8192 + 4096 + wvi * 512);       \
  } while (0)

#define BARRIER asm volatile("s_barrier" ::: "memory")

__device__ __forceinline__ void gemm_core(const unsigned short* __restrict__ Ap,
                                          const unsigned short* __restrict__ Bp,
                                          unsigned short* lds, int rt, int ct,
                                          f32x4 (&acc)[8][4]) {
  const int tid = threadIdx.x;
  const int lane = tid & 63, wvi = tid >> 6;
  const int wm = wvi >> 2, wn = wvi & 3;
  const int quad = lane >> 4, l16 = lane & 15;
  const int srow = wvi * 8 + (lane >> 3);
  const int scol = ((lane & 7) ^ (lane >> 3)) << 3;
  const int ck0 = (quad ^ (l16 & 7)) << 3;
  const int ck1 = ((4 + quad) ^ (l16 & 7)) << 3;
  const int aro = (wm * 128 + l16) << 6;
  const int bro = (wn * 64 + l16) << 6;
  const int rb = rt * 256, cb = ct * 256;

#pragma unroll
  for (int i = 0; i < 8; ++i)
#pragma unroll
    for (int j = 0; j < 4; ++j) acc[i][j] = f32x4{0.f, 0.f, 0.f, 0.f};

  STGH(Bp, cb, 0, 0, 16384);
  STGH(Bp, cb, 0, 1, 16384);
  STGH(Ap, rb, 0, 0, 0);
  STGH(Ap, rb, 0, 1, 0);
  STGH(Bp, cb, 1, 0, 49152);
  STGH(Bp, cb, 1, 1, 49152);
  asm volatile("s_waitcnt vmcnt(4)" ::: "memory");
  BARRIER;

#pragma unroll 2
  for (int t = 0; t < 32; ++t) {
    const unsigned short* ab = lds + ((t & 1) << 15);
    const unsigned short* bb = ab + 16384;
    const int pn = ((t + 1) & 1) << 15;
    const int pc = ((t & 1) << 15) + 16384;
    short8 aq[4][2], b0f[2][2], b1f[2][2];

    // ---------- phase 0: quadrant (qm0,qn0) ----------
#pragma unroll
    for (int mi = 0; mi < 4; ++mi) {
      aq[mi][0] = __builtin_bit_cast(short8, *(const u32x4*)(ab + aro + mi * 1024 + ck0));
      aq[mi][1] = __builtin_bit_cast(short8, *(const u32x4*)(ab + aro + mi * 1024 + ck1));
    }
#pragma unroll
    for (int ni = 0; ni < 2; ++ni) {
      b0f[ni][0] = __builtin_bit_cast(short8, *(const u32x4*)(bb + bro + ni * 1024 + ck0));
      b0f[ni][1] = __builtin_bit_cast(short8, *(const u32x4*)(bb + bro + ni * 1024 + ck1));
    }
    if (t < 31) STGH(Ap, rb, t + 1, 0, pn);
    BARRIER;
    __builtin_amdgcn_s_setprio(1);
#pragma unroll
    for (int k = 0; k < 2; ++k)
#pragma unroll
      for (int mi = 0; mi < 4; ++mi)
#pragma unroll
        for (int ni = 0; ni < 2; ++ni)
          acc[mi][ni] =
              __builtin_amdgcn_mfma_f32_16x16x32_bf16(aq[mi][k], b0f[ni][k], acc[mi][ni], 0, 0, 0);
    __builtin_amdgcn_s_setprio(0);
    BARRIER;

    // ---------- phase 1: quadrant (qm0,qn1) ----------
#pragma unroll
    for (int ni = 0; ni < 2; ++ni) {
      b1f[ni][0] = __builtin_bit_cast(short8, *(const u32x4*)(bb + bro + 2048 + ni * 1024 + ck0));
      b1f[ni][1] = __builtin_bit_cast(short8, *(const u32x4*)(bb + bro + 2048 + ni * 1024 + ck1));
    }
    if (t < 31) STGH(Ap, rb, t + 1, 1, pn);
    BARRIER;
    __builtin_amdgcn_s_setprio(1);
#pragma unroll
    for (int k = 0; k < 2; ++k)
#pragma unroll
      for (int mi = 0; mi < 4; ++mi)
#pragma unroll
        for (int ni = 0; ni < 2; ++ni)
          acc[mi][2 + ni] = __builtin_amdgcn_mfma_f32_16x16x32_bf16(aq[mi][k], b1f[ni][k],
                                                                    acc[mi][2 + ni], 0, 0, 0);
    __builtin_amdgcn_s_setprio(0);
    BARRIER;

    // ---------- phase 2: quadrant (qm1,qn1) ----------
#pragma unroll
    for (int mi = 0; mi < 4; ++mi) {
      aq[mi][0] = __builtin_bit_cast(short8, *(const u32x4*)(ab + aro + 4096 + mi * 1024 + ck0));
      aq[mi][1] = __builtin_bit_cast(short8, *(const u32x4*)(ab + aro + 4096 + mi * 1024 + ck1));
    }
    if (t < 30) STGH(Bp, cb, t + 2, 0, pc);
    BARRIER;
    __builtin_amdgcn_s_setprio(1);
#pragma unroll
    for (int k = 0; k < 2; ++k)
#pragma unroll
      for (int mi = 0; mi < 4; ++mi)
#pragma unroll
        for (int ni = 0; ni < 2; ++ni)
          acc[4 + mi][2 + ni] = __builtin_amdgcn_mfma_f32_16x16x32_bf16(
              aq[mi][k], b1f[ni][k], acc[4 + mi][2 + ni], 0, 0, 0);
    __builtin_amdgcn_s_setprio(0);
    BARRIER;

    // ---------- phase 3: quadrant (qm1,qn0); boundary wait ----------
    if (t < 30) STGH(Bp, cb, t + 2, 1, pc);
    BARRIER;
    __builtin_amdgcn_s_setprio(1);
#pragma unroll
    for (int k = 0; k < 2; ++k)
#pragma unroll
      for (int mi = 0; mi < 4; ++mi)
#pragma unroll
        for (int ni = 0; ni < 2; ++ni)
          acc[4 + mi][ni] = __builtin_amdgcn_mfma_f32_16x16x32_bf16(aq[mi][k], b0f[ni][k],
                                                                    acc[4 + mi][ni], 0, 0, 0);
    __builtin_amdgcn_s_setprio(0);
    if (t < 30) {
      asm volatile("s_waitcnt vmcnt(4)" ::: "memory");
      BARRIER;
    } else if (t == 30) {
      asm volatile("s_waitcnt vmcnt(0)" ::: "memory");
      BARRIER;
    }
  }
}

// ---------- QKV GEMM (merged): z=0 Q, z=1 K (chunk-XOR out-swizzle), z=2 V ----------
__global__ __launch_bounds__(512, 2) void gemm_qkv(const unsigned short* __restrict__ A,
                                                   const unsigned short* __restrict__ W0,
                                                   const unsigned short* __restrict__ W1,
                                                   const unsigned short* __restrict__ W2,
                                                   unsigned short* __restrict__ q_out,
                                                   unsigned short* __restrict__ k_out,
                                                   unsigned short* __restrict__ v_out) {
  __shared__ unsigned short lds[65536];
  const int ct = blockIdx.x, rt = blockIdx.y, z = blockIdx.z;
  const unsigned short* W = (z == 0) ? W0 : (z == 1) ? W1 : W2;
  unsigned short* outb = (z == 0) ? q_out : (z == 1) ? k_out : v_out;
  f32x4 acc[8][4];
  gemm_core(A, W, lds, rt, ct, acc);

  const int tid = threadIdx.x;
  const int lane = tid & 63, wvi = tid >> 6;
  const int wm = wvi >> 2, wn = wvi & 3;
  const int quad = lane >> 4, l16 = lane & 15;
#pragma unroll
  for (int mi = 0; mi < 8; ++mi)
#pragma unroll
    for (int ni = 0; ni < 4; ++ni)
#pragma unroll
      for (int r = 0; r < 4; ++r) {
        int row_g = rt * 256 + wm * 128 + mi * 16 + quad * 4 + r;
        int col_g = ct * 256 + wn * 64 + ni * 16 + l16;
        float v = acc[mi][ni][r];
        int b = row_g >> 11, s = row_g & (SS - 1);
        int h = col_g >> 7, d = col_g & (HD - 1);
        size_t rowbase = (((size_t)(b * HH + h)) * SS + (size_t)s) * HD;
        if (z == 1) {  // K: chunk-XOR swizzle (chunk = d>>3 XOR s&7) for attn staging
          outb[rowbase + (size_t)((((d >> 3) ^ (s & 7)) << 3) | (d & 7))] = f2bf(v);
        } else {  // Q, V standard
          outb[rowbase + (size_t)d] = f2bf(v);
        }
      }
}

// ---------- output GEMM: fp32 + bias ----------
__global__ __launch_bounds__(512, 2) void gemm_out(const unsigned short* __restrict__ A,
                                                   const unsigned short* __restrict__ W,
                                                   float* __restrict__ outf,
                                                   const float* __restrict__ bias) {
  __shared__ unsigned short lds[65536];
  const int ct = blockIdx.x, rt = blockIdx.y;
  f32x4 acc[8][4];
  gemm_core(A, W, lds, rt, ct, acc);

  const int tid = threadIdx.x;
  const int lane = tid & 63, wvi = tid >> 6;
  const int wm = wvi >> 2, wn = wvi & 3;
  const int quad = lane >> 4, l16 = lane & 15;
#pragma unroll
  for (int mi = 0; mi < 8; ++mi)
#pragma unroll
    for (int ni = 0; ni < 4; ++ni)
#pragma unroll
      for (int r = 0; r < 4; ++r) {
        int row_g = rt * 256 + wm * 128 + mi * 16 + quad * 4 + r;
        int col_g = ct * 256 + wn * 64 + ni * 16 + l16;
        outf[(size_t)row_g * DD + col_g] = acc[mi][ni][r] + bias[col_g];
      }
}

// ---------- RoPE: 4 pairs (16B) per thread; q pre-scaled by 1/sqrt(hd); k swizzle-aware ----------
__global__ void rope_kernel(unsigned short* __restrict__ qb, unsigned short* __restrict__ kb) {
  int id = blockIdx.x * blockDim.x + threadIdx.x;
  int c = id & 15;                 // logical chunk of 8 d-values
  int s = (id >> 4) & (SS - 1);
  int bhb = id >> 15;              // 0..127
  unsigned short* p;
  float psc;
  if (bhb < 64) {
    p = qb + ((size_t)bhb * SS + s) * HD + c * 8;
    psc = 0.08838834764831845f;    // fold softmax scale into q
  } else {
    p = kb + ((size_t)(bhb & 63) * SS + s) * HD + ((c ^ (s & 7)) << 3);
    psc = 1.0f;
  }
  u32x4 w = *(u32x4*)p;
  const float nl = -9.210340371976184f / 64.0f;  // -ln(10000)/64
  u32x4 o;
#pragma unroll
  for (int j = 0; j < 4; ++j) {
    int pi = c * 4 + j;
    float inv = __expf((float)pi * nl);
    float ang = (float)s * inv;
    float cs = __cosf(ang), sn = __sinf(ang);
    float e = bf2f((unsigned short)(w[j] & 0xffffu));
    float od = bf2f((unsigned short)(w[j] >> 16));
    float r1 = (e * cs - od * sn) * psc;
    float r2 = (e * sn + od * cs) * psc;
    o[j] = (unsigned int)f2bf(r1) | ((unsigned int)f2bf(r2) << 16);
  }
  *(u32x4*)p = o;
}

// ---------- Flash attention v7: v4 structure + double-buffered prefetch ----------
// 8 waves x 16 q-rows = 128 q-rows/block; kv-tile 64. Grid 1024, XCD-bijective swizzle.
// Double-buffered Kt/Vt: at tile-top issue V global->reg loads + K gl16 for t+1 into the
// idle buffer; QK/softmax/PV on tile t hides the latency; ds_write V(t+1); ONE
// __syncthreads per tile (v4 had 3, all with exposed staging latency).
// K pre-swizzled in global (gemm_qkv z=1 + rope); Vt stride-64 chunk-XOR swizzle (v5,
// verified); P per-wave private. LDS 80KB -> 2 blocks/CU x 8 waves = 16 waves/CU.
__global__ __launch_bounds__(512, 2) void attn_kernel(const unsigned short* __restrict__ qb,
                                                      const unsigned short* __restrict__ kb,
                                                      const unsigned short* __restrict__ vb,
                                                      unsigned short* __restrict__ ctxb) {
  __shared__ unsigned short lds[40960];  // Kt[2][8192] | Vt[2][8192] | P[8][1024]
  const int tid = threadIdx.x;
  const int g0 = blockIdx.x;
  const int g = (g0 & 7) * 128 + (g0 >> 3);  // XCD-bijective (1024 % 8 == 0)
  const int bh = g >> 4;             // 0..63
  const int qa = 15 - (g & 15);      // longest-first within bh
  const int lane = tid & 63, wvi = tid >> 6;
  const int quad = lane >> 4, l16 = lane & 15;
  const size_t bhq = (size_t)bh * SS * HD;
  const int qrow = qa * 128 + wvi * 16;
  const int b = bh >> 4, h = bh & (HH - 1);
  unsigned short* Pw = lds + 32768 + wvi * 1024;
  const int vrr = tid & 31, vcd = tid >> 5;  // V staging: kv-pair, d-chunk
  const int krow = wvi * 4 + (lane >> 4);    // K staging row within 32-row round
  const int kcol = (lane & 15) * 8;
  f32x4 zero = {0.f, 0.f, 0.f, 0.f};

  short8 qf[4];
#pragma unroll
  for (int ks = 0; ks < 4; ++ks)
    qf[ks] = __builtin_bit_cast(
        short8, *(const u32x4*)(qb + bhq + (size_t)(qrow + l16) * HD + ks * 32 + quad * 8));

  f32x4 acc[8];
#pragma unroll
  for (int dt = 0; dt < 8; ++dt) acc[dt] = zero;
  float lpart[4] = {0.f, 0.f, 0.f, 0.f};

  const int ntile = 2 * qa + 2;

  // ---- prologue: stage tile 0 into buffer 0
  {
    const unsigned short* vsrc = vb + bhq + (size_t)(2 * vrr) * HD + vcd * 8;
    u32x4 pva = *(const u32x4*)vsrc;
    u32x4 pvb = *(const u32x4*)(vsrc + HD);
    gl16(kb + bhq + (size_t)krow * HD + kcol, lds + krow * 128);
    gl16(kb + bhq + (size_t)(32 + krow) * HD + kcol, lds + (32 + krow) * 128);
    u16x8 va = __builtin_bit_cast(u16x8, pva);
    u16x8 vb2 = __builtin_bit_cast(u16x8, pvb);
    unsigned int* vw = (unsigned int*)(lds + 16384);
#pragma unroll
    for (int j = 0; j < 8; ++j)
      vw[(vcd * 8 + j) * 32 + (((vrr >> 2) ^ j) << 2) + (vrr & 3)] =
          (unsigned int)va[j] | ((unsigned int)vb2[j] << 16);
    __syncthreads();
  }

  for (int kt = 0; kt < ntile; ++kt) {
    const int kv0 = kt * 64;
    const int cur = (kt & 1) * 8192;
    const int nxt = ((kt + 1) & 1) * 8192;
    const unsigned short* Kc = lds + cur;
    const unsigned short* Vc = lds + 16384 + cur;
    const bool hasnext = (kt + 1 < ntile);

    // ---- issue prefetch of tile t+1 (V loads first, then K gl16)
    u32x4 pva, pvb;
    if (hasnext) {
      const int kvn = kv0 + 64;
      const unsigned short* vsrc = vb + bhq + (size_t)(kvn + 2 * vrr) * HD + vcd * 8;
      pva = *(const u32x4*)vsrc;
      pvb = *(const u32x4*)(vsrc + HD);
      gl16(kb + bhq + (size_t)(kvn + krow) * HD + kcol, lds + nxt + krow * 128);
      gl16(kb + bhq + (size_t)(kvn + 32 + krow) * HD + kcol, lds + nxt + (32 + krow) * 128);
    }

    // ---- QK^T from current Kt (XOR-unswizzle reads)
    f32x4 sc[4];
#pragma unroll
    for (int nt = 0; nt < 4; ++nt) {
      sc[nt] = zero;
#pragma unroll
      for (int ks = 0; ks < 4; ++ks) {
        short8 kf = __builtin_bit_cast(
            short8, *(const u32x4*)(Kc + (nt * 16 + l16) * 128 +
                                    (((ks * 4 + quad) ^ (l16 & 7)) << 3)));
        sc[nt] = __builtin_amdgcn_mfma_f32_16x16x32_bf16(qf[ks], kf, sc[nt], 0, 0, 0);
      }
    }

    // ---- softmax (fixed max), P -> per-wave private LDS (verified XOR formulas)
    const bool dm = (kt >= ntile - 2);
    if (dm) {
#pragma unroll
      for (int r = 0; r < 4; ++r) {
        int row = qrow + quad * 4 + r;
        int prow = quad * 4 + r;
#pragma unroll
        for (int nt = 0; nt < 4; ++nt) {
          int col = kv0 + nt * 16 + l16;
          float pv = (col > row) ? 0.f : __expf(sc[nt][r]);
          lpart[r] += pv;
          int el = prow * 64 +
                   ((((nt * 2 + (l16 >> 3)) + prow + 4 * (prow >> 3)) & 7) << 3) + (l16 & 7);
          Pw[el] = f2bf(pv);
        }
      }
    } else {
#pragma unroll
      for (int r = 0; r < 4; ++r) {
        int prow = quad * 4 + r;
#pragma unroll
        for (int nt = 0; nt < 4; ++nt) {
          float pv = __expf(sc[nt][r]);
          lpart[r] += pv;
          int el = prow * 64 +
                   ((((nt * 2 + (l16 >> 3)) + prow + 4 * (prow >> 3)) & 7) << 3) + (l16 & 7);
          Pw[el] = f2bf(pv);
        }
      }
    }

    // ---- PV from current Vt (swizzled stride-64 reads)
#pragma unroll
    for (int ks2 = 0; ks2 < 2; ++ks2) {
      short8 pfrag = __builtin_bit_cast(
          short8, *(const u32x4*)(Pw + l16 * 64 +
                                  ((((ks2 * 4 + quad) + l16 + 4 * (l16 >> 3)) & 7) << 3)));
#pragma unroll
      for (int dt = 0; dt < 8; ++dt) {
        short8 vf = __builtin_bit_cast(
            short8, *(const u32x4*)(Vc + (dt * 16 + l16) * 64 +
                                    (((ks2 * 4 + quad) ^ (l16 & 7)) << 3)));
        acc[dt] = __builtin_amdgcn_mfma_f32_16x16x32_bf16(pfrag, vf, acc[dt], 0, 0, 0);
      }
    }

    // ---- write prefetched V(t+1) into the idle buffer, then one barrier
    if (hasnext) {
      u16x8 va = __builtin_bit_cast(u16x8, pva);
      u16x8 vb2 = __builtin_bit_cast(u16x8, pvb);
      unsigned int* vw = (unsigned int*)(lds + 16384 + nxt);
#pragma unroll
      for (int j = 0; j < 8; ++j)
        vw[(vcd * 8 + j) * 32 + (((vrr >> 2) ^ j) << 2) + (vrr & 3)] =
            (unsigned int)va[j] | ((unsigned int)vb2[j] << 16);
    }
    __syncthreads();
  }

  // epilogue: one 16-lane reduction per row, ctx (B,S,D) bf16
  float rl[4];
#pragma unroll
  for (int r = 0; r < 4; ++r) {
    float rs = lpart[r];
#pragma unroll
    for (int off = 1; off < 16; off <<= 1) rs += __shfl_xor(rs, off, 64);
    rl[r] = 1.0f / rs;
  }
#pragma unroll
  for (int dt = 0; dt < 8; ++dt)
#pragma unroll
    for (int r = 0; r < 4; ++r) {
      int row = qrow + quad * 4 + r;
      ctxb[((size_t)(b * SS + row)) * DD + h * HD + dt * 16 + l16] = f2bf(acc[dt][r] * rl[r]);
    }
}

// ---------- launch ----------
extern "C" void kernel_launch(void* const* d_in, const int* in_sizes, int n_in,
                              void* d_out, int out_size, void* d_ws, size_t ws_size,
                              hipStream_t stream) {
  const float* x = (const float*)d_in[0];
  const float* wq = (const float*)d_in[1];
  const float* wk = (const float*)d_in[2];
  const float* wv = (const float*)d_in[3];
  const float* wo = (const float*)d_in[4];
  const float* bo = (const float*)d_in[5];
  float* out = (float*)d_out;

  unsigned short* xb = (unsigned short*)d_ws;
  unsigned short* wqb = xb + (size_t)MM * DD;
  unsigned short* wkb = wqb + (size_t)DD * DD;
  unsigned short* wvb = wkb + (size_t)DD * DD;
  unsigned short* wob = wvb + (size_t)DD * DD;
  unsigned short* qb = wob + (size_t)DD * DD;
  unsigned short* kb = qb + (size_t)MM * DD;
  unsigned short* vb = kb + (size_t)MM * DD;
  unsigned short* ctxb = vb + (size_t)MM * DD;

  cast_all<<<(2 * MM * DD / 4) / 256, 256, 0, stream>>>(x, wq, wk, wv, wo, xb, wqb, wkb, wvb, wob);

  dim3 gg(DD / 256, MM / 256, 3);
  gemm_qkv<<<gg, 512, 0, stream>>>(xb, wqb, wkb, wvb, qb, kb, vb);

  rope_kernel<<<(128 * 2048 * 16) / 256, 256, 0, stream>>>(qb, kb);

  attn_kernel<<<1024, 512, 0, stream>>>(qb, kb, vb, ctxb);

  dim3 go(DD / 256, MM / 256);
  gemm_out<<<go, 512, 0, stream>>>(ctxb, wob, out, bo);
}

// Round 6
// 559.249 us; speedup vs baseline: 1.9023x; 1.0238x over previous
//
#include <hip/hip_runtime.h>

// ---------- types ----------
typedef short short8 __attribute__((ext_vector_type(8)));
typedef float f32x4 __attribute__((ext_vector_type(4)));
typedef unsigned int u32x4 __attribute__((ext_vector_type(4)));
typedef unsigned short u16x4 __attribute__((ext_vector_type(4)));
typedef unsigned short u16x8 __attribute__((ext_vector_type(8)));

// ---------- bf16 helpers ----------
__device__ __forceinline__ unsigned short f2bf(float f) {
  unsigned int u = __builtin_bit_cast(unsigned int, f);
  u += 0x7fffu + ((u >> 16) & 1u);
  return (unsigned short)(u >> 16);
}
__device__ __forceinline__ float bf2f(unsigned short h) {
  unsigned int u = ((unsigned int)h) << 16;
  return __builtin_bit_cast(float, u);
}

// ---------- async global->LDS (16B per lane; LDS dst = wave base + lane*16) ----------
__device__ __forceinline__ void gl16(const unsigned short* g, unsigned short* l) {
  __builtin_amdgcn_global_load_lds((const __attribute__((address_space(1))) unsigned int*)g,
                                   (__attribute__((address_space(3))) unsigned int*)l, 16, 0, 0);
}

// ---------- problem constants ----------
#define BB 4
#define SS 2048
#define DD 2048
#define HH 16
#define HD 128
#define MM (BB * SS)  // 8192

// ---------- merged cast fp32 -> bf16 (x + 4 weights) ----------
__global__ void cast_all(const float* __restrict__ x, const float* __restrict__ wq,
                         const float* __restrict__ wk, const float* __restrict__ wv,
                         const float* __restrict__ wo, unsigned short* __restrict__ xb,
                         unsigned short* __restrict__ wqb, unsigned short* __restrict__ wkb,
                         unsigned short* __restrict__ wvb, unsigned short* __restrict__ wob) {
  int i = blockIdx.x * blockDim.x + threadIdx.x;
  const int X4 = (MM * DD) / 4;  // 4194304
  const int W4 = (DD * DD) / 4;  // 1048576
  const float* src;
  unsigned short* dst;
  int off;
  if (i < X4) {
    src = x; dst = xb; off = i;
  } else {
    int t = i - X4;
    int w = t >> 20;
    off = t & (W4 - 1);
    src = (w == 0) ? wq : (w == 1) ? wk : (w == 2) ? wv : wo;
    dst = (w == 0) ? wqb : (w == 1) ? wkb : (w == 2) ? wvb : wob;
  }
  f32x4 v = ((const f32x4*)src)[off];
  u16x4 o;
  o[0] = f2bf(v[0]); o[1] = f2bf(v[1]); o[2] = f2bf(v[2]); o[3] = f2bf(v[3]);
  ((u16x4*)dst)[off] = o;
}

// =====================================================================================
// 256x256 8-phase GEMM core (T2 swizzle + T3/T4 counted vmcnt + T5 setprio).
// (unchanged — verified; bank conflicts measured 0)
// =====================================================================================
#define STGH(P, R0, t, h, moff)                                                     \
  do {                                                                              \
    const unsigned short* _s =                                                      \
        (P) + (size_t)((R0) + (h) * 128 + srow) * DD + (size_t)((t) * 64 + scol);   \
    gl16(_s, lds + (moff) + (h) * 8192 + wvi * 512);                                \
    gl16(_s + (size_t)64 * DD, lds + (moff) + (h) * 8192 + 4096 + wvi * 512);       \
  } while (0)

#define BARRIER asm volatile("s_barrier" ::: "memory")

__device__ __forceinline__ void gemm_core(const unsigned short* __restrict__ Ap,
                                          const unsigned short* __restrict__ Bp,
                                          unsigned short* lds, int rt, int ct,
                                          f32x4 (&acc)[8][4]) {
  const int tid = threadIdx.x;
  const int lane = tid & 63, wvi = tid >> 6;
  const int wm = wvi >> 2, wn = wvi & 3;
  const int quad = lane >> 4, l16 = lane & 15;
  const int srow = wvi * 8 + (lane >> 3);
  const int scol = ((lane & 7) ^ (lane >> 3)) << 3;
  const int ck0 = (quad ^ (l16 & 7)) << 3;
  const int ck1 = ((4 + quad) ^ (l16 & 7)) << 3;
  const int aro = (wm * 128 + l16) << 6;
  const int bro = (wn * 64 + l16) << 6;
  const int rb = rt * 256, cb = ct * 256;

#pragma unroll
  for (int i = 0; i < 8; ++i)
#pragma unroll
    for (int j = 0; j < 4; ++j) acc[i][j] = f32x4{0.f, 0.f, 0.f, 0.f};

  STGH(Bp, cb, 0, 0, 16384);
  STGH(Bp, cb, 0, 1, 16384);
  STGH(Ap, rb, 0, 0, 0);
  STGH(Ap, rb, 0, 1, 0);
  STGH(Bp, cb, 1, 0, 49152);
  STGH(Bp, cb, 1, 1, 49152);
  asm volatile("s_waitcnt vmcnt(4)" ::: "memory");
  BARRIER;

#pragma unroll 2
  for (int t = 0; t < 32; ++t) {
    const unsigned short* ab = lds + ((t & 1) << 15);
    const unsigned short* bb = ab + 16384;
    const int pn = ((t + 1) & 1) << 15;
    const int pc = ((t & 1) << 15) + 16384;
    short8 aq[4][2], b0f[2][2], b1f[2][2];

    // ---------- phase 0: quadrant (qm0,qn0) ----------
#pragma unroll
    for (int mi = 0; mi < 4; ++mi) {
      aq[mi][0] = __builtin_bit_cast(short8, *(const u32x4*)(ab + aro + mi * 1024 + ck0));
      aq[mi][1] = __builtin_bit_cast(short8, *(const u32x4*)(ab + aro + mi * 1024 + ck1));
    }
#pragma unroll
    for (int ni = 0; ni < 2; ++ni) {
      b0f[ni][0] = __builtin_bit_cast(short8, *(const u32x4*)(bb + bro + ni * 1024 + ck0));
      b0f[ni][1] = __builtin_bit_cast(short8, *(const u32x4*)(bb + bro + ni * 1024 + ck1));
    }
    if (t < 31) STGH(Ap, rb, t + 1, 0, pn);
    BARRIER;
    __builtin_amdgcn_s_setprio(1);
#pragma unroll
    for (int k = 0; k < 2; ++k)
#pragma unroll
      for (int mi = 0; mi < 4; ++mi)
#pragma unroll
        for (int ni = 0; ni < 2; ++ni)
          acc[mi][ni] =
              __builtin_amdgcn_mfma_f32_16x16x32_bf16(aq[mi][k], b0f[ni][k], acc[mi][ni], 0, 0, 0);
    __builtin_amdgcn_s_setprio(0);
    BARRIER;

    // ---------- phase 1: quadrant (qm0,qn1) ----------
#pragma unroll
    for (int ni = 0; ni < 2; ++ni) {
      b1f[ni][0] = __builtin_bit_cast(short8, *(const u32x4*)(bb + bro + 2048 + ni * 1024 + ck0));
      b1f[ni][1] = __builtin_bit_cast(short8, *(const u32x4*)(bb + bro + 2048 + ni * 1024 + ck1));
    }
    if (t < 31) STGH(Ap, rb, t + 1, 1, pn);
    BARRIER;
    __builtin_amdgcn_s_setprio(1);
#pragma unroll
    for (int k = 0; k < 2; ++k)
#pragma unroll
      for (int mi = 0; mi < 4; ++mi)
#pragma unroll
        for (int ni = 0; ni < 2; ++ni)
          acc[mi][2 + ni] = __builtin_amdgcn_mfma_f32_16x16x32_bf16(aq[mi][k], b1f[ni][k],
                                                                    acc[mi][2 + ni], 0, 0, 0);
    __builtin_amdgcn_s_setprio(0);
    BARRIER;

    // ---------- phase 2: quadrant (qm1,qn1) ----------
#pragma unroll
    for (int mi = 0; mi < 4; ++mi) {
      aq[mi][0] = __builtin_bit_cast(short8, *(const u32x4*)(ab + aro + 4096 + mi * 1024 + ck0));
      aq[mi][1] = __builtin_bit_cast(short8, *(const u32x4*)(ab + aro + 4096 + mi * 1024 + ck1));
    }
    if (t < 30) STGH(Bp, cb, t + 2, 0, pc);
    BARRIER;
    __builtin_amdgcn_s_setprio(1);
#pragma unroll
    for (int k = 0; k < 2; ++k)
#pragma unroll
      for (int mi = 0; mi < 4; ++mi)
#pragma unroll
        for (int ni = 0; ni < 2; ++ni)
          acc[4 + mi][2 + ni] = __builtin_amdgcn_mfma_f32_16x16x32_bf16(
              aq[mi][k], b1f[ni][k], acc[4 + mi][2 + ni], 0, 0, 0);
    __builtin_amdgcn_s_setprio(0);
    BARRIER;

    // ---------- phase 3: quadrant (qm1,qn0); boundary wait ----------
    if (t < 30) STGH(Bp, cb, t + 2, 1, pc);
    BARRIER;
    __builtin_amdgcn_s_setprio(1);
#pragma unroll
    for (int k = 0; k < 2; ++k)
#pragma unroll
      for (int mi = 0; mi < 4; ++mi)
#pragma unroll
        for (int ni = 0; ni < 2; ++ni)
          acc[4 + mi][ni] = __builtin_amdgcn_mfma_f32_16x16x32_bf16(aq[mi][k], b0f[ni][k],
                                                                    acc[4 + mi][ni], 0, 0, 0);
    __builtin_amdgcn_s_setprio(0);
    if (t < 30) {
      asm volatile("s_waitcnt vmcnt(4)" ::: "memory");
      BARRIER;
    } else if (t == 30) {
      asm volatile("s_waitcnt vmcnt(0)" ::: "memory");
      BARRIER;
    }
  }
}

// ---------- QKV GEMM (merged) + fused RoPE: z=0 Q (roped+scaled), z=1 K (roped,
// chunk-XOR out-swizzle), z=2 V (standard). XCD-chunked bijective grid swizzle. ----------
__global__ __launch_bounds__(512, 2) void gemm_qkv(const unsigned short* __restrict__ A,
                                                   const unsigned short* __restrict__ W0,
                                                   const unsigned short* __restrict__ W1,
                                                   const unsigned short* __restrict__ W2,
                                                   unsigned short* __restrict__ q_out,
                                                   unsigned short* __restrict__ k_out,
                                                   unsigned short* __restrict__ v_out) {
  __shared__ unsigned short lds[65536];
  // T1: chunked XCD swizzle over 768 blocks (768 % 8 == 0 -> bijective).
  const int id = (blockIdx.z << 8) | (blockIdx.y << 3) | blockIdx.x;
  const int nid = (id & 7) * 96 + (id >> 3);
  const int z = nid >> 8;
  const int rt = (nid & 255) >> 3, ct = nid & 7;
  const unsigned short* W = (z == 0) ? W0 : (z == 1) ? W1 : W2;
  unsigned short* outb = (z == 0) ? q_out : (z == 1) ? k_out : v_out;
  f32x4 acc[8][4];
  gemm_core(A, W, lds, rt, ct, acc);

  const int tid = threadIdx.x;
  const int lane = tid & 63, wvi = tid >> 6;
  const int wm = wvi >> 2, wn = wvi & 3;
  const int quad = lane >> 4, l16 = lane & 15;

  if (z == 2) {
    // V: standard (B,H,S,hd) scatter writes
#pragma unroll
    for (int mi = 0; mi < 8; ++mi)
#pragma unroll
      for (int ni = 0; ni < 4; ++ni)
#pragma unroll
        for (int r = 0; r < 4; ++r) {
          int row_g = rt * 256 + wm * 128 + mi * 16 + quad * 4 + r;
          int col_g = ct * 256 + wn * 64 + ni * 16 + l16;
          int b = row_g >> 11, s = row_g & (SS - 1);
          int h = col_g >> 7, d = col_g & (HD - 1);
          outb[(((size_t)(b * HH + h)) * SS + (size_t)s) * HD + (size_t)d] = f2bf(acc[mi][ni][r]);
        }
  } else {
    // Q/K with fused RoPE. Pair (d, d^1) lives in lanes (l16, l16^1): one shfl_xor.
    // Q additionally pre-scaled by 1/sqrt(hd) (softmax scale folded in).
    const float psc = (z == 0) ? 0.08838834764831845f : 1.0f;
    const bool odd = (l16 & 1) != 0;
    const float nl = -0.14391156831212936f;  // -ln(10000)/64
    float inv4[4];
#pragma unroll
    for (int ni = 0; ni < 4; ++ni)
      inv4[ni] = __expf((float)((((wn * 64 + ni * 16 + l16) & 127) >> 1)) * nl);
#pragma unroll
    for (int mi = 0; mi < 8; ++mi)
#pragma unroll
      for (int ni = 0; ni < 4; ++ni)
#pragma unroll
        for (int r = 0; r < 4; ++r) {
          int row_g = rt * 256 + wm * 128 + mi * 16 + quad * 4 + r;
          int col_g = ct * 256 + wn * 64 + ni * 16 + l16;
          int b = row_g >> 11, s = row_g & (SS - 1);
          int h = col_g >> 7, d = col_g & (HD - 1);
          float v = acc[mi][ni][r];
          float p = __shfl_xor(v, 1, 64);
          float ang = (float)s * inv4[ni];
          float cs = __cosf(ang), sn = __sinf(ang);
          float o = (odd ? (p * sn + v * cs) : (v * cs - p * sn)) * psc;
          size_t rowbase = (((size_t)(b * HH + h)) * SS + (size_t)s) * HD;
          if (z == 1) {  // K: chunk-XOR swizzle (chunk = d>>3 XOR s&7) for attn staging
            outb[rowbase + (size_t)((((d >> 3) ^ (s & 7)) << 3) | (d & 7))] = f2bf(o);
          } else {
            outb[rowbase + (size_t)d] = f2bf(o);
          }
        }
  }
}

// ---------- output GEMM: fp32 + bias; XCD-chunked grid swizzle ----------
__global__ __launch_bounds__(512, 2) void gemm_out(const unsigned short* __restrict__ A,
                                                   const unsigned short* __restrict__ W,
                                                   float* __restrict__ outf,
                                                   const float* __restrict__ bias) {
  __shared__ unsigned short lds[65536];
  const int id = (blockIdx.y << 3) | blockIdx.x;          // 0..255
  const int nid = (id & 7) * 32 + (id >> 3);              // bijective (256 % 8 == 0)
  const int rt = nid >> 3, ct = nid & 7;
  f32x4 acc[8][4];
  gemm_core(A, W, lds, rt, ct, acc);

  const int tid = threadIdx.x;
  const int lane = tid & 63, wvi = tid >> 6;
  const int wm = wvi >> 2, wn = wvi & 3;
  const int quad = lane >> 4, l16 = lane & 15;
#pragma unroll
  for (int mi = 0; mi < 8; ++mi)
#pragma unroll
    for (int ni = 0; ni < 4; ++ni)
#pragma unroll
      for (int r = 0; r < 4; ++r) {
        int row_g = rt * 256 + wm * 128 + mi * 16 + quad * 4 + r;
        int col_g = ct * 256 + wn * 64 + ni * 16 + l16;
        outf[(size_t)row_g * DD + col_g] = acc[mi][ni][r] + bias[col_g];
      }
}

// ---------- Flash attention v7: v4 structure + double-buffered prefetch ----------
// (unchanged — verified: attn 248 -> ~170 us)
__global__ __launch_bounds__(512, 2) void attn_kernel(const unsigned short* __restrict__ qb,
                                                      const unsigned short* __restrict__ kb,
                                                      const unsigned short* __restrict__ vb,
                                                      unsigned short* __restrict__ ctxb) {
  __shared__ unsigned short lds[40960];  // Kt[2][8192] | Vt[2][8192] | P[8][1024]
  const int tid = threadIdx.x;
  const int g0 = blockIdx.x;
  const int g = (g0 & 7) * 128 + (g0 >> 3);  // XCD-bijective (1024 % 8 == 0)
  const int bh = g >> 4;             // 0..63
  const int qa = 15 - (g & 15);      // longest-first within bh
  const int lane = tid & 63, wvi = tid >> 6;
  const int quad = lane >> 4, l16 = lane & 15;
  const size_t bhq = (size_t)bh * SS * HD;
  const int qrow = qa * 128 + wvi * 16;
  const int b = bh >> 4, h = bh & (HH - 1);
  unsigned short* Pw = lds + 32768 + wvi * 1024;
  const int vrr = tid & 31, vcd = tid >> 5;  // V staging: kv-pair, d-chunk
  const int krow = wvi * 4 + (lane >> 4);    // K staging row within 32-row round
  const int kcol = (lane & 15) * 8;
  f32x4 zero = {0.f, 0.f, 0.f, 0.f};

  short8 qf[4];
#pragma unroll
  for (int ks = 0; ks < 4; ++ks)
    qf[ks] = __builtin_bit_cast(
        short8, *(const u32x4*)(qb + bhq + (size_t)(qrow + l16) * HD + ks * 32 + quad * 8));

  f32x4 acc[8];
#pragma unroll
  for (int dt = 0; dt < 8; ++dt) acc[dt] = zero;
  float lpart[4] = {0.f, 0.f, 0.f, 0.f};

  const int ntile = 2 * qa + 2;

  // ---- prologue: stage tile 0 into buffer 0
  {
    const unsigned short* vsrc = vb + bhq + (size_t)(2 * vrr) * HD + vcd * 8;
    u32x4 pva = *(const u32x4*)vsrc;
    u32x4 pvb = *(const u32x4*)(vsrc + HD);
    gl16(kb + bhq + (size_t)krow * HD + kcol, lds + krow * 128);
    gl16(kb + bhq + (size_t)(32 + krow) * HD + kcol, lds + (32 + krow) * 128);
    u16x8 va = __builtin_bit_cast(u16x8, pva);
    u16x8 vb2 = __builtin_bit_cast(u16x8, pvb);
    unsigned int* vw = (unsigned int*)(lds + 16384);
#pragma unroll
    for (int j = 0; j < 8; ++j)
      vw[(vcd * 8 + j) * 32 + (((vrr >> 2) ^ j) << 2) + (vrr & 3)] =
          (unsigned int)va[j] | ((unsigned int)vb2[j] << 16);
    __syncthreads();
  }

  for (int kt = 0; kt < ntile; ++kt) {
    const int kv0 = kt * 64;
    const int cur = (kt & 1) * 8192;
    const int nxt = ((kt + 1) & 1) * 8192;
    const unsigned short* Kc = lds + cur;
    const unsigned short* Vc = lds + 16384 + cur;
    const bool hasnext = (kt + 1 < ntile);

    // ---- issue prefetch of tile t+1 (V loads first, then K gl16)
    u32x4 pva, pvb;
    if (hasnext) {
      const int kvn = kv0 + 64;
      const unsigned short* vsrc = vb + bhq + (size_t)(kvn + 2 * vrr) * HD + vcd * 8;
      pva = *(const u32x4*)vsrc;
      pvb = *(const u32x4*)(vsrc + HD);
      gl16(kb + bhq + (size_t)(kvn + krow) * HD + kcol, lds + nxt + krow * 128);
      gl16(kb + bhq + (size_t)(kvn + 32 + krow) * HD + kcol, lds + nxt + (32 + krow) * 128);
    }

    // ---- QK^T from current Kt (XOR-unswizzle reads)
    f32x4 sc[4];
#pragma unroll
    for (int nt = 0; nt < 4; ++nt) {
      sc[nt] = zero;
#pragma unroll
      for (int ks = 0; ks < 4; ++ks) {
        short8 kf = __builtin_bit_cast(
            short8, *(const u32x4*)(Kc + (nt * 16 + l16) * 128 +
                                    (((ks * 4 + quad) ^ (l16 & 7)) << 3)));
        sc[nt] = __builtin_amdgcn_mfma_f32_16x16x32_bf16(qf[ks], kf, sc[nt], 0, 0, 0);
      }
    }

    // ---- softmax (fixed max), P -> per-wave private LDS (verified XOR formulas)
    const bool dm = (kt >= ntile - 2);
    if (dm) {
#pragma unroll
      for (int r = 0; r < 4; ++r) {
        int row = qrow + quad * 4 + r;
        int prow = quad * 4 + r;
#pragma unroll
        for (int nt = 0; nt < 4; ++nt) {
          int col = kv0 + nt * 16 + l16;
          float pv = (col > row) ? 0.f : __expf(sc[nt][r]);
          lpart[r] += pv;
          int el = prow * 64 +
                   ((((nt * 2 + (l16 >> 3)) + prow + 4 * (prow >> 3)) & 7) << 3) + (l16 & 7);
          Pw[el] = f2bf(pv);
        }
      }
    } else {
#pragma unroll
      for (int r = 0; r < 4; ++r) {
        int prow = quad * 4 + r;
#pragma unroll
        for (int nt = 0; nt < 4; ++nt) {
          float pv = __expf(sc[nt][r]);
          lpart[r] += pv;
          int el = prow * 64 +
                   ((((nt * 2 + (l16 >> 3)) + prow + 4 * (prow >> 3)) & 7) << 3) + (l16 & 7);
          Pw[el] = f2bf(pv);
        }
      }
    }

    // ---- PV from current Vt (swizzled stride-64 reads)
#pragma unroll
    for (int ks2 = 0; ks2 < 2; ++ks2) {
      short8 pfrag = __builtin_bit_cast(
          short8, *(const u32x4*)(Pw + l16 * 64 +
                                  ((((ks2 * 4 + quad) + l16 + 4 * (l16 >> 3)) & 7) << 3)));
#pragma unroll
      for (int dt = 0; dt < 8; ++dt) {
        short8 vf = __builtin_bit_cast(
            short8, *(const u32x4*)(Vc + (dt * 16 + l16) * 64 +
                                    (((ks2 * 4 + quad) ^ (l16 & 7)) << 3)));
        acc[dt] = __builtin_amdgcn_mfma_f32_16x16x32_bf16(pfrag, vf, acc[dt], 0, 0, 0);
      }
    }

    // ---- write prefetched V(t+1) into the idle buffer, then one barrier
    if (hasnext) {
      u16x8 va = __builtin_bit_cast(u16x8, pva);
      u16x8 vb2 = __builtin_bit_cast(u16x8, pvb);
      unsigned int* vw = (unsigned int*)(lds + 16384 + nxt);
#pragma unroll
      for (int j = 0; j < 8; ++j)
        vw[(vcd * 8 + j) * 32 + (((vrr >> 2) ^ j) << 2) + (vrr & 3)] =
            (unsigned int)va[j] | ((unsigned int)vb2[j] << 16);
    }
    __syncthreads();
  }

  // epilogue: one 16-lane reduction per row, ctx (B,S,D) bf16
  float rl[4];
#pragma unroll
  for (int r = 0; r < 4; ++r) {
    float rs = lpart[r];
#pragma unroll
    for (int off = 1; off < 16; off <<= 1) rs += __shfl_xor(rs, off, 64);
    rl[r] = 1.0f / rs;
  }
#pragma unroll
  for (int dt = 0; dt < 8; ++dt)
#pragma unroll
    for (int r = 0; r < 4; ++r) {
      int row = qrow + quad * 4 + r;
      ctxb[((size_t)(b * SS + row)) * DD + h * HD + dt * 16 + l16] = f2bf(acc[dt][r] * rl[r]);
    }
}

// ---------- launch ----------
extern "C" void kernel_launch(void* const* d_in, const int* in_sizes, int n_in,
                              void* d_out, int out_size, void* d_ws, size_t ws_size,
                              hipStream_t stream) {
  const float* x = (const float*)d_in[0];
  const float* wq = (const float*)d_in[1];
  const float* wk = (const float*)d_in[2];
  const float* wv = (const float*)d_in[3];
  const float* wo = (const float*)d_in[4];
  const float* bo = (const float*)d_in[5];
  float* out = (float*)d_out;

  unsigned short* xb = (unsigned short*)d_ws;
  unsigned short* wqb = xb + (size_t)MM * DD;
  unsigned short* wkb = wqb + (size_t)DD * DD;
  unsigned short* wvb = wkb + (size_t)DD * DD;
  unsigned short* wob = wvb + (size_t)DD * DD;
  unsigned short* qb = wob + (size_t)DD * DD;
  unsigned short* kb = qb + (size_t)MM * DD;
  unsigned short* vb = kb + (size_t)MM * DD;
  unsigned short* ctxb = vb + (size_t)MM * DD;

  cast_all<<<(2 * MM * DD / 4) / 256, 256, 0, stream>>>(x, wq, wk, wv, wo, xb, wqb, wkb, wvb, wob);

  dim3 gg(DD / 256, MM / 256, 3);
  gemm_qkv<<<gg, 512, 0, stream>>>(xb, wqb, wkb, wvb, qb, kb, vb);

  attn_kernel<<<1024, 512, 0, stream>>>(qb, kb, vb, ctxb);

  dim3 go(DD / 256, MM / 256);
  gemm_out<<<go, 512, 0, stream>>>(ctxb, wob, out, bo);
}

// Round 7
// 541.963 us; speedup vs baseline: 1.9629x; 1.0319x over previous
//
#include <hip/hip_runtime.h>

// ---------- types ----------
typedef short short8 __attribute__((ext_vector_type(8)));
typedef float f32x4 __attribute__((ext_vector_type(4)));
typedef unsigned int u32x4 __attribute__((ext_vector_type(4)));
typedef unsigned short u16x4 __attribute__((ext_vector_type(4)));
typedef unsigned short u16x8 __attribute__((ext_vector_type(8)));

// ---------- bf16 helpers ----------
__device__ __forceinline__ unsigned short f2bf(float f) {
  unsigned int u = __builtin_bit_cast(unsigned int, f);
  u += 0x7fffu + ((u >> 16) & 1u);
  return (unsigned short)(u >> 16);
}
__device__ __forceinline__ float bf2f(unsigned short h) {
  unsigned int u = ((unsigned int)h) << 16;
  return __builtin_bit_cast(float, u);
}

// ---------- async global->LDS (16B per lane; LDS dst = wave base + lane*16) ----------
__device__ __forceinline__ void gl16(const unsigned short* g, unsigned short* l) {
  __builtin_amdgcn_global_load_lds((const __attribute__((address_space(1))) unsigned int*)g,
                                   (__attribute__((address_space(3))) unsigned int*)l, 16, 0, 0);
}

// ---------- problem constants ----------
#define BB 4
#define SS 2048
#define DD 2048
#define HH 16
#define HD 128
#define MM (BB * SS)  // 8192

// ---------- merged cast fp32 -> bf16 (x + 4 weights) ----------
__global__ void cast_all(const float* __restrict__ x, const float* __restrict__ wq,
                         const float* __restrict__ wk, const float* __restrict__ wv,
                         const float* __restrict__ wo, unsigned short* __restrict__ xb,
                         unsigned short* __restrict__ wqb, unsigned short* __restrict__ wkb,
                         unsigned short* __restrict__ wvb, unsigned short* __restrict__ wob) {
  int i = blockIdx.x * blockDim.x + threadIdx.x;
  const int X4 = (MM * DD) / 4;  // 4194304
  const int W4 = (DD * DD) / 4;  // 1048576
  const float* src;
  unsigned short* dst;
  int off;
  if (i < X4) {
    src = x; dst = xb; off = i;
  } else {
    int t = i - X4;
    int w = t >> 20;
    off = t & (W4 - 1);
    src = (w == 0) ? wq : (w == 1) ? wk : (w == 2) ? wv : wo;
    dst = (w == 0) ? wqb : (w == 1) ? wkb : (w == 2) ? wvb : wob;
  }
  f32x4 v = ((const f32x4*)src)[off];
  u16x4 o;
  o[0] = f2bf(v[0]); o[1] = f2bf(v[1]); o[2] = f2bf(v[2]); o[3] = f2bf(v[3]);
  ((u16x4*)dst)[off] = o;
}

// =====================================================================================
// 256x256 8-phase GEMM core (T2 swizzle + T3/T4 counted vmcnt + T5 setprio).
// (unchanged — verified; bank conflicts measured 0)
// =====================================================================================
#define STGH(P, R0, t, h, moff)                                                     \
  do {                                                                              \
    const unsigned short* _s =                                                      \
        (P) + (size_t)((R0) + (h) * 128 + srow) * DD + (size_t)((t) * 64 + scol);   \
    gl16(_s, lds + (moff) + (h) * 8192 + wvi * 512);                                \
    gl16(_s + (size_t)64 * DD, lds + (moff) + (h) * 8192 + 4096 + wvi * 512);       \
  } while (0)

#define BARRIER asm volatile("s_barrier" ::: "memory")

__device__ __forceinline__ void gemm_core(const unsigned short* __restrict__ Ap,
                                          const unsigned short* __restrict__ Bp,
                                          unsigned short* lds, int rt, int ct,
                                          f32x4 (&acc)[8][4]) {
  const int tid = threadIdx.x;
  const int lane = tid & 63, wvi = tid >> 6;
  const int wm = wvi >> 2, wn = wvi & 3;
  const int quad = lane >> 4, l16 = lane & 15;
  const int srow = wvi * 8 + (lane >> 3);
  const int scol = ((lane & 7) ^ (lane >> 3)) << 3;
  const int ck0 = (quad ^ (l16 & 7)) << 3;
  const int ck1 = ((4 + quad) ^ (l16 & 7)) << 3;
  const int aro = (wm * 128 + l16) << 6;
  const int bro = (wn * 64 + l16) << 6;
  const int rb = rt * 256, cb = ct * 256;

#pragma unroll
  for (int i = 0; i < 8; ++i)
#pragma unroll
    for (int j = 0; j < 4; ++j) acc[i][j] = f32x4{0.f, 0.f, 0.f, 0.f};

  STGH(Bp, cb, 0, 0, 16384);
  STGH(Bp, cb, 0, 1, 16384);
  STGH(Ap, rb, 0, 0, 0);
  STGH(Ap, rb, 0, 1, 0);
  STGH(Bp, cb, 1, 0, 49152);
  STGH(Bp, cb, 1, 1, 49152);
  asm volatile("s_waitcnt vmcnt(4)" ::: "memory");
  BARRIER;

#pragma unroll 2
  for (int t = 0; t < 32; ++t) {
    const unsigned short* ab = lds + ((t & 1) << 15);
    const unsigned short* bb = ab + 16384;
    const int pn = ((t + 1) & 1) << 15;
    const int pc = ((t & 1) << 15) + 16384;
    short8 aq[4][2], b0f[2][2], b1f[2][2];

    // ---------- phase 0: quadrant (qm0,qn0) ----------
#pragma unroll
    for (int mi = 0; mi < 4; ++mi) {
      aq[mi][0] = __builtin_bit_cast(short8, *(const u32x4*)(ab + aro + mi * 1024 + ck0));
      aq[mi][1] = __builtin_bit_cast(short8, *(const u32x4*)(ab + aro + mi * 1024 + ck1));
    }
#pragma unroll
    for (int ni = 0; ni < 2; ++ni) {
      b0f[ni][0] = __builtin_bit_cast(short8, *(const u32x4*)(bb + bro + ni * 1024 + ck0));
      b0f[ni][1] = __builtin_bit_cast(short8, *(const u32x4*)(bb + bro + ni * 1024 + ck1));
    }
    if (t < 31) STGH(Ap, rb, t + 1, 0, pn);
    BARRIER;
    __builtin_amdgcn_s_setprio(1);
#pragma unroll
    for (int k = 0; k < 2; ++k)
#pragma unroll
      for (int mi = 0; mi < 4; ++mi)
#pragma unroll
        for (int ni = 0; ni < 2; ++ni)
          acc[mi][ni] =
              __builtin_amdgcn_mfma_f32_16x16x32_bf16(aq[mi][k], b0f[ni][k], acc[mi][ni], 0, 0, 0);
    __builtin_amdgcn_s_setprio(0);
    BARRIER;

    // ---------- phase 1: quadrant (qm0,qn1) ----------
#pragma unroll
    for (int ni = 0; ni < 2; ++ni) {
      b1f[ni][0] = __builtin_bit_cast(short8, *(const u32x4*)(bb + bro + 2048 + ni * 1024 + ck0));
      b1f[ni][1] = __builtin_bit_cast(short8, *(const u32x4*)(bb + bro + 2048 + ni * 1024 + ck1));
    }
    if (t < 31) STGH(Ap, rb, t + 1, 1, pn);
    BARRIER;
    __builtin_amdgcn_s_setprio(1);
#pragma unroll
    for (int k = 0; k < 2; ++k)
#pragma unroll
      for (int mi = 0; mi < 4; ++mi)
#pragma unroll
        for (int ni = 0; ni < 2; ++ni)
          acc[mi][2 + ni] = __builtin_amdgcn_mfma_f32_16x16x32_bf16(aq[mi][k], b1f[ni][k],
                                                                    acc[mi][2 + ni], 0, 0, 0);
    __builtin_amdgcn_s_setprio(0);
    BARRIER;

    // ---------- phase 2: quadrant (qm1,qn1) ----------
#pragma unroll
    for (int mi = 0; mi < 4; ++mi) {
      aq[mi][0] = __builtin_bit_cast(short8, *(const u32x4*)(ab + aro + 4096 + mi * 1024 + ck0));
      aq[mi][1] = __builtin_bit_cast(short8, *(const u32x4*)(ab + aro + 4096 + mi * 1024 + ck1));
    }
    if (t < 30) STGH(Bp, cb, t + 2, 0, pc);
    BARRIER;
    __builtin_amdgcn_s_setprio(1);
#pragma unroll
    for (int k = 0; k < 2; ++k)
#pragma unroll
      for (int mi = 0; mi < 4; ++mi)
#pragma unroll
        for (int ni = 0; ni < 2; ++ni)
          acc[4 + mi][2 + ni] = __builtin_amdgcn_mfma_f32_16x16x32_bf16(
              aq[mi][k], b1f[ni][k], acc[4 + mi][2 + ni], 0, 0, 0);
    __builtin_amdgcn_s_setprio(0);
    BARRIER;

    // ---------- phase 3: quadrant (qm1,qn0); boundary wait ----------
    if (t < 30) STGH(Bp, cb, t + 2, 1, pc);
    BARRIER;
    __builtin_amdgcn_s_setprio(1);
#pragma unroll
    for (int k = 0; k < 2; ++k)
#pragma unroll
      for (int mi = 0; mi < 4; ++mi)
#pragma unroll
        for (int ni = 0; ni < 2; ++ni)
          acc[4 + mi][ni] = __builtin_amdgcn_mfma_f32_16x16x32_bf16(aq[mi][k], b0f[ni][k],
                                                                    acc[4 + mi][ni], 0, 0, 0);
    __builtin_amdgcn_s_setprio(0);
    if (t < 30) {
      asm volatile("s_waitcnt vmcnt(4)" ::: "memory");
      BARRIER;
    } else if (t == 30) {
      asm volatile("s_waitcnt vmcnt(0)" ::: "memory");
      BARRIER;
    }
  }
}

// ---------- QKV GEMM (merged) + fused RoPE: z=0 Q (roped+scaled), z=1 K (roped,
// chunk-XOR out-swizzle), z=2 V (standard). XCD-chunked bijective grid swizzle. ----------
__global__ __launch_bounds__(512, 2) void gemm_qkv(const unsigned short* __restrict__ A,
                                                   const unsigned short* __restrict__ W0,
                                                   const unsigned short* __restrict__ W1,
                                                   const unsigned short* __restrict__ W2,
                                                   unsigned short* __restrict__ q_out,
                                                   unsigned short* __restrict__ k_out,
                                                   unsigned short* __restrict__ v_out) {
  __shared__ unsigned short lds[65536];
  // T1: chunked XCD swizzle over 768 blocks (768 % 8 == 0 -> bijective).
  const int id = (blockIdx.z << 8) | (blockIdx.y << 3) | blockIdx.x;
  const int nid = (id & 7) * 96 + (id >> 3);
  const int z = nid >> 8;
  const int rt = (nid & 255) >> 3, ct = nid & 7;
  const unsigned short* W = (z == 0) ? W0 : (z == 1) ? W1 : W2;
  unsigned short* outb = (z == 0) ? q_out : (z == 1) ? k_out : v_out;
  f32x4 acc[8][4];
  gemm_core(A, W, lds, rt, ct, acc);

  const int tid = threadIdx.x;
  const int lane = tid & 63, wvi = tid >> 6;
  const int wm = wvi >> 2, wn = wvi & 3;
  const int quad = lane >> 4, l16 = lane & 15;

  if (z == 2) {
    // V: standard (B,H,S,hd) scatter writes
#pragma unroll
    for (int mi = 0; mi < 8; ++mi)
#pragma unroll
      for (int ni = 0; ni < 4; ++ni)
#pragma unroll
        for (int r = 0; r < 4; ++r) {
          int row_g = rt * 256 + wm * 128 + mi * 16 + quad * 4 + r;
          int col_g = ct * 256 + wn * 64 + ni * 16 + l16;
          int b = row_g >> 11, s = row_g & (SS - 1);
          int h = col_g >> 7, d = col_g & (HD - 1);
          outb[(((size_t)(b * HH + h)) * SS + (size_t)s) * HD + (size_t)d] = f2bf(acc[mi][ni][r]);
        }
  } else {
    // Q/K with fused RoPE. Pair (d, d^1) lives in lanes (l16, l16^1): one shfl_xor.
    // Q additionally pre-scaled by 1/sqrt(hd) (softmax scale folded in).
    const float psc = (z == 0) ? 0.08838834764831845f : 1.0f;
    const bool odd = (l16 & 1) != 0;
    const float nl = -0.14391156831212936f;  // -ln(10000)/64
    float inv4[4];
#pragma unroll
    for (int ni = 0; ni < 4; ++ni)
      inv4[ni] = __expf((float)((((wn * 64 + ni * 16 + l16) & 127) >> 1)) * nl);
#pragma unroll
    for (int mi = 0; mi < 8; ++mi)
#pragma unroll
      for (int ni = 0; ni < 4; ++ni)
#pragma unroll
        for (int r = 0; r < 4; ++r) {
          int row_g = rt * 256 + wm * 128 + mi * 16 + quad * 4 + r;
          int col_g = ct * 256 + wn * 64 + ni * 16 + l16;
          int b = row_g >> 11, s = row_g & (SS - 1);
          int h = col_g >> 7, d = col_g & (HD - 1);
          float v = acc[mi][ni][r];
          float p = __shfl_xor(v, 1, 64);
          float ang = (float)s * inv4[ni];
          float cs = __cosf(ang), sn = __sinf(ang);
          float o = (odd ? (p * sn + v * cs) : (v * cs - p * sn)) * psc;
          size_t rowbase = (((size_t)(b * HH + h)) * SS + (size_t)s) * HD;
          if (z == 1) {  // K: chunk-XOR swizzle (chunk = d>>3 XOR s&7) for attn staging
            outb[rowbase + (size_t)((((d >> 3) ^ (s & 7)) << 3) | (d & 7))] = f2bf(o);
          } else {
            outb[rowbase + (size_t)d] = f2bf(o);
          }
        }
  }
}

// ---------- output GEMM: fp32 + bias; XCD-chunked grid swizzle ----------
__global__ __launch_bounds__(512, 2) void gemm_out(const unsigned short* __restrict__ A,
                                                   const unsigned short* __restrict__ W,
                                                   float* __restrict__ outf,
                                                   const float* __restrict__ bias) {
  __shared__ unsigned short lds[65536];
  const int id = (blockIdx.y << 3) | blockIdx.x;          // 0..255
  const int nid = (id & 7) * 32 + (id >> 3);              // bijective (256 % 8 == 0)
  const int rt = nid >> 3, ct = nid & 7;
  f32x4 acc[8][4];
  gemm_core(A, W, lds, rt, ct, acc);

  const int tid = threadIdx.x;
  const int lane = tid & 63, wvi = tid >> 6;
  const int wm = wvi >> 2, wn = wvi & 3;
  const int quad = lane >> 4, l16 = lane & 15;
#pragma unroll
  for (int mi = 0; mi < 8; ++mi)
#pragma unroll
    for (int ni = 0; ni < 4; ++ni)
#pragma unroll
      for (int r = 0; r < 4; ++r) {
        int row_g = rt * 256 + wm * 128 + mi * 16 + quad * 4 + r;
        int col_g = ct * 256 + wn * 64 + ni * 16 + l16;
        outf[(size_t)row_g * DD + col_g] = acc[mi][ni][r] + bias[col_g];
      }
}

// ---------- Flash attention v9: 32 q-rows/wave (kf/vf shared by 2 row-blocks) on the
// v7 prefetch pipeline. 4 waves x 32 rows = 128 rows/block; kv-tile 64; grid 1024
// (XCD-bijective, longest-first). Kt double-buffered (gl16 prefetch), Vt SINGLE-buffered
// (reg prefetch, written after PV under a second barrier), P per-wave private.
// LDS 64KB -> 2 blocks/CU = 8 waves/CU (same TLP as v7, half the LDS bytes/FLOP).
__global__ __launch_bounds__(256, 2) void attn_kernel(const unsigned short* __restrict__ qb,
                                                      const unsigned short* __restrict__ kb,
                                                      const unsigned short* __restrict__ vb,
                                                      unsigned short* __restrict__ ctxb) {
  __shared__ unsigned short lds[32768];  // Kt[2][8192] | Vt[8192] | P[4][2048]
  const int tid = threadIdx.x;
  const int g0 = blockIdx.x;
  const int g = (g0 & 7) * 128 + (g0 >> 3);  // XCD-bijective (1024 % 8 == 0)
  const int bh = g >> 4;             // 0..63
  const int qa = 15 - (g & 15);      // longest-first within bh
  const int lane = tid & 63, wvi = tid >> 6;   // wvi in [0,4)
  const int quad = lane >> 4, l16 = lane & 15;
  const size_t bhq = (size_t)bh * SS * HD;
  const int qrow = qa * 128 + wvi * 32;
  const int b = bh >> 4, h = bh & (HH - 1);
  unsigned short* Pw = lds + 24576 + wvi * 2048;
  unsigned short* Vt = lds + 16384;
  const int kcol = l16 * 8;
  f32x4 zero = {0.f, 0.f, 0.f, 0.f};

  short8 qf[2][4];
#pragma unroll
  for (int rb = 0; rb < 2; ++rb)
#pragma unroll
    for (int ks = 0; ks < 4; ++ks)
      qf[rb][ks] = __builtin_bit_cast(
          short8,
          *(const u32x4*)(qb + bhq + (size_t)(qrow + rb * 16 + l16) * HD + ks * 32 + quad * 8));

  f32x4 acc[2][8];
#pragma unroll
  for (int rb = 0; rb < 2; ++rb)
#pragma unroll
    for (int dt = 0; dt < 8; ++dt) acc[rb][dt] = zero;
  float lpart[2][4] = {{0.f, 0.f, 0.f, 0.f}, {0.f, 0.f, 0.f, 0.f}};

  const int ntile = 2 * qa + 2;

  // ---- prologue: K(0) via gl16 -> Kt[0]; V(0) via regs -> Vt
  {
    u32x4 pva0, pvb0, pva1, pvb1;
    {
      const unsigned short* vs0 = vb + bhq + (size_t)(2 * (tid & 31)) * HD + (tid >> 5) * 8;
      pva0 = *(const u32x4*)vs0;
      pvb0 = *(const u32x4*)(vs0 + HD);
      const int u = tid + 256;
      const unsigned short* vs1 = vb + bhq + (size_t)(2 * (u & 31)) * HD + (u >> 5) * 8;
      pva1 = *(const u32x4*)vs1;
      pvb1 = *(const u32x4*)(vs1 + HD);
    }
#pragma unroll
    for (int r = 0; r < 4; ++r)
      gl16(kb + bhq + (size_t)(r * 16 + wvi * 4 + quad) * HD + kcol,
           lds + (r * 16 + wvi * 4) * 128);
    unsigned int* vw = (unsigned int*)Vt;
    {
      int rr = tid & 31, c = tid >> 5;
      u16x8 va = __builtin_bit_cast(u16x8, pva0);
      u16x8 vb2 = __builtin_bit_cast(u16x8, pvb0);
#pragma unroll
      for (int j = 0; j < 8; ++j)
        vw[(c * 8 + j) * 32 + (((rr >> 2) ^ j) << 2) + (rr & 3)] =
            (unsigned int)va[j] | ((unsigned int)vb2[j] << 16);
      const int u = tid + 256;
      rr = u & 31; c = u >> 5;
      va = __builtin_bit_cast(u16x8, pva1);
      vb2 = __builtin_bit_cast(u16x8, pvb1);
#pragma unroll
      for (int j = 0; j < 8; ++j)
        vw[(c * 8 + j) * 32 + (((rr >> 2) ^ j) << 2) + (rr & 3)] =
            (unsigned int)va[j] | ((unsigned int)vb2[j] << 16);
    }
    __syncthreads();
  }

  for (int kt = 0; kt < ntile; ++kt) {
    const int kv0 = kt * 64;
    const unsigned short* Kc = lds + (kt & 1) * 8192;
    const int nxt = ((kt + 1) & 1) * 8192;
    const bool hasnext = (kt + 1 < ntile);

    // ---- issue prefetch of tile t+1: V -> regs, K -> gl16 into idle K buffer
    u32x4 pva0, pvb0, pva1, pvb1;
    if (hasnext) {
      const int kvn = kv0 + 64;
      const unsigned short* vs0 = vb + bhq + (size_t)(kvn + 2 * (tid & 31)) * HD + (tid >> 5) * 8;
      pva0 = *(const u32x4*)vs0;
      pvb0 = *(const u32x4*)(vs0 + HD);
      const int u = tid + 256;
      const unsigned short* vs1 = vb + bhq + (size_t)(kvn + 2 * (u & 31)) * HD + (u >> 5) * 8;
      pva1 = *(const u32x4*)vs1;
      pvb1 = *(const u32x4*)(vs1 + HD);
#pragma unroll
      for (int r = 0; r < 4; ++r)
        gl16(kb + bhq + (size_t)(kvn + r * 16 + wvi * 4 + quad) * HD + kcol,
             lds + nxt + (r * 16 + wvi * 4) * 128);
    }

    // ---- QK^T: kf read once, feeds both row-blocks
    f32x4 sc0[4], sc1[4];
#pragma unroll
    for (int nt = 0; nt < 4; ++nt) {
      sc0[nt] = zero;
      sc1[nt] = zero;
#pragma unroll
      for (int ks = 0; ks < 4; ++ks) {
        short8 kf = __builtin_bit_cast(
            short8, *(const u32x4*)(Kc + (nt * 16 + l16) * 128 +
                                    (((ks * 4 + quad) ^ (l16 & 7)) << 3)));
        sc0[nt] = __builtin_amdgcn_mfma_f32_16x16x32_bf16(qf[0][ks], kf, sc0[nt], 0, 0, 0);
        sc1[nt] = __builtin_amdgcn_mfma_f32_16x16x32_bf16(qf[1][ks], kf, sc1[nt], 0, 0, 0);
      }
    }

    // ---- softmax (fixed max), P -> per-wave private LDS (v5-verified formulas)
    const bool dm = (kt >= ntile - 2);
    if (dm) {
#pragma unroll
      for (int r = 0; r < 4; ++r) {
        int p15 = quad * 4 + r;
#pragma unroll
        for (int nt = 0; nt < 4; ++nt) {
          int col = kv0 + nt * 16 + l16;
          int el = p15 * 64 + ((((nt * 2 + (l16 >> 3)) + p15 + 4 * (p15 >> 3)) & 7) << 3) +
                   (l16 & 7);
          float pv0 = (col > qrow + p15) ? 0.f : __expf(sc0[nt][r]);
          lpart[0][r] += pv0;
          Pw[el] = f2bf(pv0);
          float pv1 = (col > qrow + 16 + p15) ? 0.f : __expf(sc1[nt][r]);
          lpart[1][r] += pv1;
          Pw[1024 + el] = f2bf(pv1);
        }
      }
    } else {
#pragma unroll
      for (int r = 0; r < 4; ++r) {
        int p15 = quad * 4 + r;
#pragma unroll
        for (int nt = 0; nt < 4; ++nt) {
          int el = p15 * 64 + ((((nt * 2 + (l16 >> 3)) + p15 + 4 * (p15 >> 3)) & 7) << 3) +
                   (l16 & 7);
          float pv0 = __expf(sc0[nt][r]);
          lpart[0][r] += pv0;
          Pw[el] = f2bf(pv0);
          float pv1 = __expf(sc1[nt][r]);
          lpart[1][r] += pv1;
          Pw[1024 + el] = f2bf(pv1);
        }
      }
    }

    // ---- PV: vf read once, feeds both row-blocks
#pragma unroll
    for (int ks2 = 0; ks2 < 2; ++ks2) {
      const int pk = (((ks2 * 4 + quad) + l16 + 4 * (l16 >> 3)) & 7) << 3;
      short8 pf0 = __builtin_bit_cast(short8, *(const u32x4*)(Pw + l16 * 64 + pk));
      short8 pf1 = __builtin_bit_cast(short8, *(const u32x4*)(Pw + 1024 + l16 * 64 + pk));
#pragma unroll
      for (int dt = 0; dt < 8; ++dt) {
        short8 vf = __builtin_bit_cast(
            short8, *(const u32x4*)(Vt + (dt * 16 + l16) * 64 +
                                    (((ks2 * 4 + quad) ^ (l16 & 7)) << 3)));
        acc[0][dt] = __builtin_amdgcn_mfma_f32_16x16x32_bf16(pf0, vf, acc[0][dt], 0, 0, 0);
        acc[1][dt] = __builtin_amdgcn_mfma_f32_16x16x32_bf16(pf1, vf, acc[1][dt], 0, 0, 0);
      }
    }

    __syncthreads();  // all waves done reading Vt (and K gl16 for t+1 drained)

    // ---- write prefetched V(t+1) into Vt, publish with second barrier
    if (hasnext) {
      unsigned int* vw = (unsigned int*)Vt;
      int rr = tid & 31, c = tid >> 5;
      u16x8 va = __builtin_bit_cast(u16x8, pva0);
      u16x8 vb2 = __builtin_bit_cast(u16x8, pvb0);
#pragma unroll
      for (int j = 0; j < 8; ++j)
        vw[(c * 8 + j) * 32 + (((rr >> 2) ^ j) << 2) + (rr & 3)] =
            (unsigned int)va[j] | ((unsigned int)vb2[j] << 16);
      const int u = tid + 256;
      rr = u & 31; c = u >> 5;
      va = __builtin_bit_cast(u16x8, pva1);
      vb2 = __builtin_bit_cast(u16x8, pvb1);
#pragma unroll
      for (int j = 0; j < 8; ++j)
        vw[(c * 8 + j) * 32 + (((rr >> 2) ^ j) << 2) + (rr & 3)] =
            (unsigned int)va[j] | ((unsigned int)vb2[j] << 16);
      __syncthreads();
    }
  }

  // epilogue: 16-lane reduction per row, ctx (B,S,D) bf16
#pragma unroll
  for (int rb = 0; rb < 2; ++rb) {
    float rl[4];
#pragma unroll
    for (int r = 0; r < 4; ++r) {
      float rs = lpart[rb][r];
#pragma unroll
      for (int off = 1; off < 16; off <<= 1) rs += __shfl_xor(rs, off, 64);
      rl[r] = 1.0f / rs;
    }
#pragma unroll
    for (int dt = 0; dt < 8; ++dt)
#pragma unroll
      for (int r = 0; r < 4; ++r) {
        int row = qrow + rb * 16 + quad * 4 + r;
        ctxb[((size_t)(b * SS + row)) * DD + h * HD + dt * 16 + l16] =
            f2bf(acc[rb][dt][r] * rl[r]);
      }
  }
}

// ---------- launch ----------
extern "C" void kernel_launch(void* const* d_in, const int* in_sizes, int n_in,
                              void* d_out, int out_size, void* d_ws, size_t ws_size,
                              hipStream_t stream) {
  const float* x = (const float*)d_in[0];
  const float* wq = (const float*)d_in[1];
  const float* wk = (const float*)d_in[2];
  const float* wv = (const float*)d_in[3];
  const float* wo = (const float*)d_in[4];
  const float* bo = (const float*)d_in[5];
  float* out = (float*)d_out;

  unsigned short* xb = (unsigned short*)d_ws;
  unsigned short* wqb = xb + (size_t)MM * DD;
  unsigned short* wkb = wqb + (size_t)DD * DD;
  unsigned short* wvb = wkb + (size_t)DD * DD;
  unsigned short* wob = wvb + (size_t)DD * DD;
  unsigned short* qb = wob + (size_t)DD * DD;
  unsigned short* kb = qb + (size_t)MM * DD;
  unsigned short* vb = kb + (size_t)MM * DD;
  unsigned short* ctxb = vb + (size_t)MM * DD;

  cast_all<<<(2 * MM * DD / 4) / 256, 256, 0, stream>>>(x, wq, wk, wv, wo, xb, wqb, wkb, wvb, wob);

  dim3 gg(DD / 256, MM / 256, 3);
  gemm_qkv<<<gg, 512, 0, stream>>>(xb, wqb, wkb, wvb, qb, kb, vb);

  attn_kernel<<<1024, 256, 0, stream>>>(qb, kb, vb, ctxb);

  dim3 go(DD / 256, MM / 256);
  gemm_out<<<go, 512, 0, stream>>>(ctxb, wob, out, bo);
}